// Round 12
// baseline (583.615 us; speedup 1.0000x reference)
//
#include <hip/hip_runtime.h>
#include <hip/hip_bf16.h>

#define DI __device__ __forceinline__

typedef float f32x4 __attribute__((ext_vector_type(4)));
typedef float f32x2 __attribute__((ext_vector_type(2)));
typedef short s16x8 __attribute__((ext_vector_type(8)));
typedef short s16x4 __attribute__((ext_vector_type(4)));
typedef unsigned u32x2 __attribute__((ext_vector_type(2)));
typedef unsigned u32x4 __attribute__((ext_vector_type(4)));

DI short f2bf(float x) {
  union { float f; unsigned u; } v; v.f = x;
  unsigned r = v.u + 0x7fffu + ((v.u >> 16) & 1u);
  return (short)(r >> 16);
}

DI float bf2f(short x) {
  union { unsigned u; float f; } v;
  v.u = ((unsigned)(unsigned short)x) << 16;
  return v.f;
}

DI unsigned cvt_pk(float lo, float hi) {  // low16 = bf16(lo), high16 = bf16(hi)
  unsigned r;
  asm("v_cvt_pk_bf16_f32 %0, %1, %2" : "=v"(r) : "v"(lo), "v"(hi));
  return r;
}

DI s16x8 pack8(f32x4 a, f32x4 b) {
  union { u32x4 u; s16x8 s; } r;
  r.u[0] = cvt_pk(a[0], a[1]); r.u[1] = cvt_pk(a[2], a[3]);
  r.u[2] = cvt_pk(b[0], b[1]); r.u[3] = cvt_pk(b[2], b[3]);
  return r.s;
}

// Fast gelu: x * sigmoid(1.5957691x + 0.0713548x^3)
DI float gelu_f(float x) {
  const float e = __expf(-x * fmaf(x * x, 0.0713548162f, 1.5957691216f));
  return __fdividef(x, 1.f + e);
}

// ---------------------------------------------------------------------------
// K1: fused prep (weights) + ctx.
//  blocks [0,1024): out-mode ctx (streamed rows, block owns i -> direct write)
//  blocks [1024,1088): in-mode STREAMED partials: block owns 16 i-rows,
//    loops j outer / i inner (16 contiguous-row loads in flight), writes
//    bf16 partial sums + f32 partial degs per (chunk, j).  No strided reads.
//  blocks [1088,2240): weight prep.
// ---------------------------------------------------------------------------
__global__ __launch_bounds__(256) void prep_ctx_kernel(
    const float* __restrict__ pair_h, const int* __restrict__ edge_mask,
    const float* __restrict__ pfnW1, const float* __restrict__ pfnW2,
    const float* __restrict__ pffW1, const float* __restrict__ pffW2,
    short* __restrict__ W1c, float* __restrict__ Wu, float* __restrict__ Whjv,
    short* __restrict__ W2T, short* __restrict__ W1Tp,
    short* __restrict__ W2Tp, float* __restrict__ out_ctx,
    short* __restrict__ pin, float* __restrict__ pdeg) {
  __shared__ float sacc[2][128];
  __shared__ float sdeg[2];
  const int t = threadIdx.x;
  if (blockIdx.x >= 1088) {  // ---- weight prep ----
    int idx = (blockIdx.x - 1088) * 256 + t;
    if (idx < 65536) {  // W1c [256 n][256 k] = [Wp | Wm]^T
      int n = idx / 256, k = idx % 256;
      float v = (k < 128) ? pfnW1[k * 256 + n] : pfnW1[(384 + k) * 256 + n];
      W1c[idx] = f2bf(v);
      return;
    }
    idx -= 65536;
    if (idx < 32768) {  // Wu f32 [128 k][256 n] = Whi + Wd
      int k = idx / 256, n = idx % 256;
      Wu[idx] = pfnW1[(128 + k) * 256 + n] + pfnW1[(384 + k) * 256 + n];
      return;
    }
    idx -= 32768;
    if (idx < 32768) {  // Whjv f32 [128 k][256 n] = Whj - Wd
      int k = idx / 256, n = idx % 256;
      Whjv[idx] = pfnW1[(256 + k) * 256 + n] - pfnW1[(384 + k) * 256 + n];
      return;
    }
    idx -= 32768;
    if (idx < 32768) {  // W2T [128 n][256 k]
      int n = idx / 256, k = idx % 256;
      W2T[idx] = f2bf(pfnW2[k * 128 + n]);
      return;
    }
    idx -= 32768;
    if (idx < 65536) {  // W1Tp [512 n][128 k]
      int n = idx / 128, k = idx % 128;
      W1Tp[idx] = f2bf(pffW1[k * 512 + n]);
      return;
    }
    idx -= 65536;
    if (idx < 65536) {  // W2Tp [128 n][512 k]
      int n = idx / 512, k = idx % 512;
      W2Tp[idx] = f2bf(pffW2[k * 128 + n]);
    }
    return;
  }
  if (blockIdx.x >= 1024) {  // ---- in-mode streamed partials ----
    const int bx = blockIdx.x - 1024;   // 0..63
    const int b = bx >> 4, c = bx & 15; // chunk c: i in [c*16, c*16+16)
    const int i0 = c * 16;
    const int d4 = (t & 31) * 4;
    const int jrow = t >> 5;            // 0..7
    for (int jo = 0; jo < 32; ++jo) {
      const int j = jo * 8 + jrow;
      f32x4 acc = {0.f, 0.f, 0.f, 0.f};
      float dg = 0.f;
#pragma unroll
      for (int i = 0; i < 16; ++i) {
        const long row = (long)(b * 256 + i0 + i) * 256 + j;
        const float m = (float)edge_mask[row];
        f32x4 v = *(const f32x4*)(pair_h + row * 128 + d4);
#pragma unroll
        for (int e = 0; e < 4; ++e) acc[e] = fmaf(m, v[e], acc[e]);
        dg += m;
      }
      u32x2 pk = {cvt_pk(acc[0], acc[1]), cvt_pk(acc[2], acc[3])};
      *(u32x2*)(pin + ((long)bx * 256 + j) * 128 + d4) = pk;
      if ((t & 31) == 0) pdeg[bx * 256 + j] = dg;
    }
    return;
  }
  // ---- out-mode ctx (streamed; block owns i) ----
  const int wg = blockIdx.x;
  const int half = t >> 7, d = t & 127;
  const int b = wg >> 8, x = wg & 255;
  float acc = 0.f, deg = 0.f;
#pragma unroll 8
  for (int y0 = 0; y0 < 256; y0 += 2) {
    const int y = y0 + half;
    const long row = (long)(b * 256 + x) * 256 + y;
    const float m = (float)edge_mask[row];
    const float v = pair_h[row * 128 + d];
    acc = fmaf(m, v, acc);
    deg += m;
  }
  sacc[half][d] = acc;
  if (d == 0) sdeg[half] = deg;
  __syncthreads();
  if (t < 128) {
    float tot = sacc[0][d] + sacc[1][d];
    float dg = fmaxf(sdeg[0] + sdeg[1], 1.f);
    out_ctx[(b * 256 + x) * 128 + d] = tot / dg;
  }
}

// ---------------------------------------------------------------------------
// K1b: reduce in-mode partials (16 chunks) and divide by deg.
// ---------------------------------------------------------------------------
__global__ __launch_bounds__(256) void inred_kernel(
    const short* __restrict__ pin, const float* __restrict__ pdeg,
    float* __restrict__ in_ctx) {
  const int tid = blockIdx.x * 256 + threadIdx.x;  // 131072 total
  const int d = tid & 127;
  const int j = (tid >> 7) & 255;
  const int b = tid >> 15;
  float s = 0.f, dg = 0.f;
#pragma unroll
  for (int c = 0; c < 16; ++c) {
    const int bx = b * 16 + c;
    s += bf2f(pin[((long)bx * 256 + j) * 128 + d]);
    dg += pdeg[bx * 256 + j];
  }
  in_ctx[(b * 256 + j) * 128 + d] = s / fmaxf(dg, 1.f);
}

// ---------------------------------------------------------------------------
// K2: node path fp32 (unchanged from R11).
// ---------------------------------------------------------------------------
__global__ __launch_bounds__(256) void node_kernel(
    const float* __restrict__ node_h, const float* __restrict__ out_ctx,
    const float* __restrict__ in_ctx, const int* __restrict__ node_mask,
    const float* __restrict__ ogW, const float* __restrict__ ogb,
    const float* __restrict__ igW, const float* __restrict__ igb,
    const float* __restrict__ nW1, const float* __restrict__ nb1,
    const float* __restrict__ nW2, const float* __restrict__ nb2,
    const float* __restrict__ fW1, const float* __restrict__ fb1,
    const float* __restrict__ fW2, const float* __restrict__ fb2,
    const float* __restrict__ g1, const float* __restrict__ be1,
    const float* __restrict__ g2, const float* __restrict__ be2,
    const float* __restrict__ Wu, const float* __restrict__ ub1,
    const float* __restrict__ Whjv, float* __restrict__ out_node,
    short* __restrict__ node_bf, short* __restrict__ u_bf,
    short* __restrict__ hjv_bf) {
  __shared__ float sh[4][896];
  __shared__ float fin[4][128];
  const int t = threadIdx.x;
  const int wv = t >> 6, lane = t & 63;
  float* const xn = sh[wv];
  float* const xo = sh[wv] + 128;
  float* const xi = sh[wv] + 256;
  float* const hh = sh[wv] + 384;
  const int row = blockIdx.x * 4 + wv;

#pragma unroll
  for (int c = 0; c < 2; ++c) {
    const int col = lane + 64 * c;
    xn[col] = node_h[row * 128 + col];
    xo[col] = out_ctx[row * 128 + col];
    xi[col] = in_ctx[row * 128 + col];
  }

  {
    float ao[2], ai[2];
#pragma unroll
    for (int c = 0; c < 2; ++c) {
      const int col = lane + 64 * c;
      ao[c] = ogb[col];
      ai[c] = igb[col];
    }
#pragma unroll 4
    for (int k = 0; k < 256; ++k) {
      float xov, xiv;
      if (k < 128) { xov = xiv = xn[k]; }
      else { xov = xo[k - 128]; xiv = xi[k - 128]; }
#pragma unroll
      for (int c = 0; c < 2; ++c) {
        const int col = lane + 64 * c;
        ao[c] += xov * ogW[k * 128 + col];
        ai[c] += xiv * igW[k * 128 + col];
      }
    }
#pragma unroll
    for (int c = 0; c < 2; ++c) {
      const int col = lane + 64 * c;
      const float go = 1.f / (1.f + __expf(-ao[c]));
      const float gi = 1.f / (1.f + __expf(-ai[c]));
      xo[col] *= go;
      xi[col] *= gi;
    }
  }

  {
    float a1[4];
#pragma unroll
    for (int c = 0; c < 4; ++c) a1[c] = nb1[lane + 64 * c];
#pragma unroll 4
    for (int k = 0; k < 384; ++k) {
      const float* src = (k < 128) ? xn : (k < 256) ? xo : xi;
      const float x = src[k & 127];
#pragma unroll
      for (int c = 0; c < 4; ++c) a1[c] += x * nW1[k * 256 + lane + 64 * c];
    }
#pragma unroll
    for (int c = 0; c < 4; ++c) hh[lane + 64 * c] = gelu_f(a1[c]);
  }
  {
    float a2[2];
#pragma unroll
    for (int c = 0; c < 2; ++c) a2[c] = nb2[lane + 64 * c];
#pragma unroll 4
    for (int k = 0; k < 256; ++k) {
      const float h = hh[k];
#pragma unroll
      for (int c = 0; c < 2; ++c) a2[c] += h * nW2[k * 128 + lane + 64 * c];
    }
    float v0 = xn[lane] + a2[0];
    float v1 = xn[lane + 64] + a2[1];
    float s = v0 + v1, ss = v0 * v0 + v1 * v1;
#pragma unroll
    for (int off = 1; off < 64; off <<= 1) {
      s += __shfl_xor(s, off, 64);
      ss += __shfl_xor(ss, off, 64);
    }
    const float m = s * (1.f / 128.f);
    const float var = ss * (1.f / 128.f) - m * m;
    const float rs = rsqrtf(var + 1e-5f);
    xn[lane] = (v0 - m) * rs * g1[lane] + be1[lane];
    xn[lane + 64] = (v1 - m) * rs * g1[lane + 64] + be1[lane + 64];
  }

  {
    float af[8];
#pragma unroll
    for (int c = 0; c < 8; ++c) af[c] = fb1[lane + 64 * c];
#pragma unroll 4
    for (int k = 0; k < 128; ++k) {
      const float x = xn[k];
#pragma unroll
      for (int c = 0; c < 8; ++c) af[c] += x * fW1[k * 512 + lane + 64 * c];
    }
#pragma unroll
    for (int c = 0; c < 8; ++c) hh[lane + 64 * c] = gelu_f(af[c]);
  }
  {
    float a2[2];
#pragma unroll
    for (int c = 0; c < 2; ++c) a2[c] = fb2[lane + 64 * c];
#pragma unroll 4
    for (int k = 0; k < 512; ++k) {
      const float h = hh[k];
#pragma unroll
      for (int c = 0; c < 2; ++c) a2[c] += h * fW2[k * 128 + lane + 64 * c];
    }
    float v0 = xn[lane] + a2[0];
    float v1 = xn[lane + 64] + a2[1];
    float s = v0 + v1, ss = v0 * v0 + v1 * v1;
#pragma unroll
    for (int off = 1; off < 64; off <<= 1) {
      s += __shfl_xor(s, off, 64);
      ss += __shfl_xor(ss, off, 64);
    }
    const float m = s * (1.f / 128.f);
    const float var = ss * (1.f / 128.f) - m * m;
    const float rs = rsqrtf(var + 1e-5f);
    const float msk = (float)node_mask[row];
    const float o0 = ((v0 - m) * rs * g2[lane] + be2[lane]) * msk;
    const float o1 = ((v1 - m) * rs * g2[lane + 64] + be2[lane + 64]) * msk;
    out_node[row * 128 + lane] = o0;
    out_node[row * 128 + lane + 64] = o1;
    node_bf[row * 128 + lane] = f2bf(o0);
    node_bf[row * 128 + lane + 64] = f2bf(o1);
    fin[wv][lane] = o0;
    fin[wv][lane + 64] = o1;
  }
  __syncthreads();
  {
    float uacc[4], hacc[4];
    const float bb = ub1[t];
#pragma unroll
    for (int r = 0; r < 4; ++r) { uacc[r] = bb; hacc[r] = 0.f; }
#pragma unroll 4
    for (int k = 0; k < 128; ++k) {
      const float wu = Wu[k * 256 + t];
      const float wh = Whjv[k * 256 + t];
#pragma unroll
      for (int r = 0; r < 4; ++r) {
        uacc[r] += fin[r][k] * wu;
        hacc[r] += fin[r][k] * wh;
      }
    }
#pragma unroll
    for (int r = 0; r < 4; ++r) {
      u_bf[(blockIdx.x * 4 + r) * 256 + t] = f2bf(uacc[r]);
      hjv_bf[(blockIdx.x * 4 + r) * 256 + t] = f2bf(hacc[r]);
    }
  }
}

// ---------------------------------------------------------------------------
// K3: fused pair kernel (UNCHANGED from R10/R11 — verified ~436us).
// ---------------------------------------------------------------------------
__global__ __launch_bounds__(512, 4) void pair_kernel(
    const float* __restrict__ pair_h, const short* __restrict__ node_bf,
    const int* __restrict__ edge_mask, const short* __restrict__ W1c,
    const short* __restrict__ W2T, const short* __restrict__ W1Tp,
    const short* __restrict__ W2Tp, const short* __restrict__ u_bf,
    const short* __restrict__ hjv_bf, const float* __restrict__ b2,
    const float* __restrict__ b1p, const float* __restrict__ b2p,
    const float* __restrict__ g1, const float* __restrict__ be1,
    const float* __restrict__ g2, const float* __restrict__ be2,
    float* __restrict__ out_pair) {
  constexpr int OFF_A = 0, OFF_H1 = 0, OFF_Y = 0, OFF_H2 = 33792,
                OFF_SCR = 67584;
  constexpr int PA = 528, PY = 272;  // byte pitches
  __shared__ __align__(16) char smem[69632];

  const int t = threadIdx.x;
  const int wg = blockIdx.x;
  const int b = wg >> 10, rem = wg & 1023;
  const int i = rem >> 2, j0 = (rem & 3) << 6;
  const int bi = (b << 8) + i;
  const long rowbase = (long)bi * 256 + j0;

  const int lane = t & 63, wv = t >> 6;
  const int lr = lane & 15, lq = lane >> 4;
  const int jb = (wv >> 2) * 32, nb2 = (wv & 3) * 32;

  // ---- P0: build A = [pair | hi*hj] bf16, padded pitch ----
  {
    const int r = t >> 3, oc = t & 7, c0 = oc * 16;
    const float* prow = pair_h + (rowbase + r) * 128 + c0;
    const short* hjrow = node_bf + (b * 256 + j0 + r) * 128 + c0;
    const short* hirow = node_bf + (b * 256 + i) * 128 + c0;
    char* arow = smem + OFF_A + r * PA;
#pragma unroll
    for (int h = 0; h < 2; ++h) {
      f32x4 p0 = *(const f32x4*)(prow + h * 8);
      f32x4 p1 = *(const f32x4*)(prow + h * 8 + 4);
      s16x8 hj = *(const s16x8*)(hjrow + h * 8);
      s16x8 hi = *(const s16x8*)(hirow + h * 8);
      *(s16x8*)(arow + c0 * 2 + h * 16) = pack8(p0, p1);
      union { u32x4 u; s16x8 s; } pd;
#pragma unroll
      for (int e = 0; e < 4; ++e)
        pd.u[e] = cvt_pk(bf2f(hi[2 * e]) * bf2f(hj[2 * e]),
                         bf2f(hi[2 * e + 1]) * bf2f(hj[2 * e + 1]));
      *(s16x8*)(arow + 256 + c0 * 2 + h * 16) = pd.s;
    }
  }
  __syncthreads();  // B1: A ready

  // ---- GEMM1: C1^T[n][j] over K=256; 4-deep w prefetch, 2-deep d roll ----
  f32x4 acc1[4][2];
#pragma unroll
  for (int jt = 0; jt < 4; ++jt)
#pragma unroll
    for (int nt = 0; nt < 2; ++nt) acc1[jt][nt] = {0.f, 0.f, 0.f, 0.f};
  {
    const int nb = wv * 32;
    const short* wp0 = W1c + (nb + lr) * 256 + lq * 8;
    const short* wp1 = W1c + (nb + 16 + lr) * 256 + lq * 8;
    s16x8 w0p[4], w1p[4];
#pragma unroll
    for (int pf = 0; pf < 4; ++pf) {
      w0p[pf] = *(const s16x8*)(wp0 + pf * 32);
      w1p[pf] = *(const s16x8*)(wp1 + pf * 32);
    }
    s16x8 dc[2][4];
#pragma unroll
    for (int pf = 0; pf < 2; ++pf)
#pragma unroll
      for (int jt = 0; jt < 4; ++jt)
        dc[pf][jt] = *(const s16x8*)(smem + OFF_A + (jt * 16 + lr) * PA +
                                     pf * 64 + lq * 16);
#pragma unroll
    for (int ks = 0; ks < 8; ++ks) {
      const int cur = ks & 1;
      s16x8 w0 = w0p[ks & 3], w1 = w1p[ks & 3];
      if (ks < 4) {
        w0p[ks & 3] = *(const s16x8*)(wp0 + (ks + 4) * 32);
        w1p[ks & 3] = *(const s16x8*)(wp1 + (ks + 4) * 32);
      }
      s16x8 d[4];
#pragma unroll
      for (int jt = 0; jt < 4; ++jt) d[jt] = dc[cur][jt];
      if (ks < 6) {
#pragma unroll
        for (int jt = 0; jt < 4; ++jt)
          dc[cur][jt] = *(const s16x8*)(smem + OFF_A + (jt * 16 + lr) * PA +
                                        (ks + 2) * 64 + lq * 16);
      }
#pragma unroll
      for (int jt = 0; jt < 4; ++jt) {
        acc1[jt][0] = __builtin_amdgcn_mfma_f32_16x16x32_bf16(w0, d[jt], acc1[jt][0], 0, 0, 0);
        acc1[jt][1] = __builtin_amdgcn_mfma_f32_16x16x32_bf16(w1, d[jt], acc1[jt][1], 0, 0, 0);
      }
    }
  }
  // pre-issue: u (H1 epilogue) + G2 first weights -- in flight across barrier
  s16x4 uv0 = *(const s16x4*)(u_bf + bi * 256 + wv * 32 + lq * 4);
  s16x4 uv1 = *(const s16x4*)(u_bf + bi * 256 + wv * 32 + 16 + lq * 4);
  const short* q2p0 = W2T + (nb2 + lr) * 256 + lq * 8;
  const short* q2p1 = W2T + (nb2 + 16 + lr) * 256 + lq * 8;
  s16x8 q2w0[4], q2w1[4];
  q2w0[0] = *(const s16x8*)q2p0;
  q2w1[0] = *(const s16x8*)q2p1;
  q2w0[1] = *(const s16x8*)(q2p0 + 32);
  q2w1[1] = *(const s16x8*)(q2p1 + 32);
  __syncthreads();  // B2: A reads done -> H1 overlay
  {
    const int nb = wv * 32;
#pragma unroll
    for (int nt = 0; nt < 2; ++nt) {
      const int n0 = nb + nt * 16 + lq * 4;
      const s16x4 uv = nt ? uv1 : uv0;
      f32x4 uu;
#pragma unroll
      for (int v = 0; v < 4; ++v) uu[v] = bf2f(uv[v]);  // u includes b1
#pragma unroll
      for (int jt = 0; jt < 4; ++jt) {
        const int j = jt * 16 + lr;
        s16x4 hv = *(const s16x4*)(hjv_bf + (b * 256 + j0 + j) * 256 + n0);
        float pre[4];
#pragma unroll
        for (int v = 0; v < 4; ++v)
          pre[v] = acc1[jt][nt][v] + uu[v] + bf2f(hv[v]);
        u32x2 pk = {cvt_pk(gelu_f(pre[0]), gelu_f(pre[1])),
                    cvt_pk(gelu_f(pre[2]), gelu_f(pre[3]))};
        *(u32x2*)(smem + OFF_H1 + j * PA + n0 * 2) = pk;
      }
    }
  }
  __syncthreads();  // B3: H1 ready

  // ---- GEMM2: x1^T[n][j] over K=256; wave -> (jb, nb2) 32x32 ----
  f32x4 x1v[2][2];
  {
    q2w0[2] = *(const s16x8*)(q2p0 + 64);
    q2w1[2] = *(const s16x8*)(q2p1 + 64);
    q2w0[3] = *(const s16x8*)(q2p0 + 96);
    q2w1[3] = *(const s16x8*)(q2p1 + 96);
    f32x4 pr[2][2];
#pragma unroll
    for (int nt = 0; nt < 2; ++nt)
#pragma unroll
      for (int jt = 0; jt < 2; ++jt)
        pr[jt][nt] = *(const f32x4*)(pair_h + (rowbase + jb + jt * 16 + lr) * 128 +
                                     nb2 + nt * 16 + lq * 4);
    s16x8 dc[2][2];
#pragma unroll
    for (int pf = 0; pf < 2; ++pf)
#pragma unroll
      for (int jt = 0; jt < 2; ++jt)
        dc[pf][jt] = *(const s16x8*)(smem + OFF_H1 + (jb + jt * 16 + lr) * PA +
                                     pf * 64 + lq * 16);
    f32x4 acc2[2][2];
#pragma unroll
    for (int jt = 0; jt < 2; ++jt)
#pragma unroll
      for (int nt = 0; nt < 2; ++nt) acc2[jt][nt] = {0.f, 0.f, 0.f, 0.f};
#pragma unroll
    for (int ks = 0; ks < 8; ++ks) {
      const int cur = ks & 1;
      s16x8 w0 = q2w0[ks & 3], w1 = q2w1[ks & 3];
      if (ks < 4) {
        q2w0[ks & 3] = *(const s16x8*)(q2p0 + (ks + 4) * 32);
        q2w1[ks & 3] = *(const s16x8*)(q2p1 + (ks + 4) * 32);
      }
      s16x8 d[2];
#pragma unroll
      for (int jt = 0; jt < 2; ++jt) d[jt] = dc[cur][jt];
      if (ks < 6) {
#pragma unroll
        for (int jt = 0; jt < 2; ++jt)
          dc[cur][jt] = *(const s16x8*)(smem + OFF_H1 + (jb + jt * 16 + lr) * PA +
                                        (ks + 2) * 64 + lq * 16);
      }
#pragma unroll
      for (int jt = 0; jt < 2; ++jt) {
        acc2[jt][0] = __builtin_amdgcn_mfma_f32_16x16x32_bf16(w0, d[jt], acc2[jt][0], 0, 0, 0);
        acc2[jt][1] = __builtin_amdgcn_mfma_f32_16x16x32_bf16(w1, d[jt], acc2[jt][1], 0, 0, 0);
      }
    }
#pragma unroll
    for (int nt = 0; nt < 2; ++nt) {
      const int n0 = nb2 + nt * 16 + lq * 4;
      f32x4 bv = *(const f32x4*)(b2 + n0);
#pragma unroll
      for (int jt = 0; jt < 2; ++jt)
        x1v[jt][nt] = acc2[jt][nt] + bv + pr[jt][nt];
    }
  }
  // ---- LN1 in-reg ----
  {
    float s[2], ss[2];
#pragma unroll
    for (int jt = 0; jt < 2; ++jt) {
      s[jt] = 0.f; ss[jt] = 0.f;
#pragma unroll
      for (int nt = 0; nt < 2; ++nt)
#pragma unroll
        for (int v = 0; v < 4; ++v) {
          const float x = x1v[jt][nt][v];
          s[jt] += x; ss[jt] += x * x;
        }
      s[jt] += __shfl_xor(s[jt], 16, 64);
      ss[jt] += __shfl_xor(ss[jt], 16, 64);
      s[jt] += __shfl_xor(s[jt], 32, 64);
      ss[jt] += __shfl_xor(ss[jt], 32, 64);
    }
    if (lq == 0) {
#pragma unroll
      for (int jt = 0; jt < 2; ++jt) {
        const int j = jb + jt * 16 + lr;
        f32x2 p = {s[jt], ss[jt]};
        *(f32x2*)(smem + OFF_SCR + j * 32 + (wv & 3) * 8) = p;
      }
    }
    __syncthreads();  // B4: H1 reads done + SCR partials visible
    float lnm[2], lnr[2];
#pragma unroll
    for (int jt = 0; jt < 2; ++jt) {
      const int j = jb + jt * 16 + lr;
      f32x4 pA = *(const f32x4*)(smem + OFF_SCR + j * 32);
      f32x4 pB = *(const f32x4*)(smem + OFF_SCR + j * 32 + 16);
      const float S = pA[0] + pA[2] + pB[0] + pB[2];
      const float SS = pA[1] + pA[3] + pB[1] + pB[3];
      const float m = S * (1.f / 128.f);
      const float var = SS * (1.f / 128.f) - m * m;
      lnm[jt] = m;
      lnr[jt] = rsqrtf(var + 1e-5f);
    }
#pragma unroll
    for (int nt = 0; nt < 2; ++nt) {
      const int n0 = nb2 + nt * 16 + lq * 4;
      f32x4 gv = *(const f32x4*)(g1 + n0);
      f32x4 bv = *(const f32x4*)(be1 + n0);
#pragma unroll
      for (int jt = 0; jt < 2; ++jt) {
        const int j = jb + jt * 16 + lr;
        float y[4];
#pragma unroll
        for (int v = 0; v < 4; ++v)
          y[v] = (x1v[jt][nt][v] - lnm[jt]) * lnr[jt] * gv[v] + bv[v];
        u32x2 pk = {cvt_pk(y[0], y[1]), cvt_pk(y[2], y[3])};
        *(u32x2*)(smem + OFF_Y + j * PY + n0 * 2) = pk;
      }
    }
  }
  // pre-issue G3-p0 first weights + edge_mask before the barrier
  const short* g3p0a = W1Tp + (wv * 32 + lr) * 128 + lq * 8;
  const short* g3p1a = W1Tp + (wv * 32 + 16 + lr) * 128 + lq * 8;
  s16x8 g3w0[4], g3w1[4];
  g3w0[0] = *(const s16x8*)g3p0a;
  g3w1[0] = *(const s16x8*)g3p1a;
  g3w0[1] = *(const s16x8*)(g3p0a + 32);
  g3w1[1] = *(const s16x8*)(g3p1a + 32);
  const int em0 = edge_mask[rowbase + jb + lr];
  const int em1 = edge_mask[rowbase + jb + 16 + lr];
  __syncthreads();  // B5: Y ready

  // ---- pff: 2 K-halves; per half GEMM3(K=128)->H2half, GEMM4 accumulates ----
  f32x4 acc4[2][2];
#pragma unroll
  for (int jt = 0; jt < 2; ++jt)
#pragma unroll
    for (int nt = 0; nt < 2; ++nt) acc4[jt][nt] = {0.f, 0.f, 0.f, 0.f};

#pragma unroll
  for (int p = 0; p < 2; ++p) {
    f32x4 acc3[4][2];
#pragma unroll
    for (int jt = 0; jt < 4; ++jt)
#pragma unroll
      for (int nt = 0; nt < 2; ++nt) acc3[jt][nt] = {0.f, 0.f, 0.f, 0.f};
    {
      const int nb3 = p * 256 + wv * 32;
      const short* wp0 = W1Tp + (nb3 + lr) * 128 + lq * 8;
      const short* wp1 = W1Tp + (nb3 + 16 + lr) * 128 + lq * 8;
      if (p == 0) {  // slots 0,1 pre-issued before barrier B5
        g3w0[2] = *(const s16x8*)(wp0 + 64);
        g3w1[2] = *(const s16x8*)(wp1 + 64);
        g3w0[3] = *(const s16x8*)(wp0 + 96);
        g3w1[3] = *(const s16x8*)(wp1 + 96);
      } else {
#pragma unroll
        for (int pf = 0; pf < 4; ++pf) {
          g3w0[pf] = *(const s16x8*)(wp0 + pf * 32);
          g3w1[pf] = *(const s16x8*)(wp1 + pf * 32);
        }
      }
#pragma unroll
      for (int ks = 0; ks < 4; ++ks) {
        s16x8 d[4];
#pragma unroll
        for (int jt = 0; jt < 4; ++jt)
          d[jt] = *(const s16x8*)(smem + OFF_Y + (jt * 16 + lr) * PY +
                                  ks * 64 + lq * 16);
#pragma unroll
        for (int jt = 0; jt < 4; ++jt) {
          acc3[jt][0] = __builtin_amdgcn_mfma_f32_16x16x32_bf16(g3w0[ks], d[jt], acc3[jt][0], 0, 0, 0);
          acc3[jt][1] = __builtin_amdgcn_mfma_f32_16x16x32_bf16(g3w1[ks], d[jt], acc3[jt][1], 0, 0, 0);
        }
      }
    }
    // pre-issue G4 weights for this half (in flight across H2-write + barrier)
    const short* qp0 = W2Tp + (nb2 + lr) * 512 + p * 256 + lq * 8;
    const short* qp1 = W2Tp + (nb2 + 16 + lr) * 512 + p * 256 + lq * 8;
    s16x8 q4w0[4], q4w1[4];
    q4w0[0] = *(const s16x8*)qp0;
    q4w1[0] = *(const s16x8*)qp1;
    q4w0[1] = *(const s16x8*)(qp0 + 32);
    q4w1[1] = *(const s16x8*)(qp1 + 32);
    if (p == 1) __syncthreads();  // B7: G4-p0 H2 reads done before overwrite
    {
#pragma unroll
      for (int nt = 0; nt < 2; ++nt) {
        const int n0l = wv * 32 + nt * 16 + lq * 4;  // local n within half
        f32x4 bv = *(const f32x4*)(b1p + p * 256 + n0l);
#pragma unroll
        for (int jt = 0; jt < 4; ++jt) {
          const int j = jt * 16 + lr;
          u32x2 pk = {cvt_pk(gelu_f(acc3[jt][nt][0] + bv[0]),
                             gelu_f(acc3[jt][nt][1] + bv[1])),
                      cvt_pk(gelu_f(acc3[jt][nt][2] + bv[2]),
                             gelu_f(acc3[jt][nt][3] + bv[3]))};
          *(u32x2*)(smem + OFF_H2 + j * PA + n0l * 2) = pk;
        }
      }
    }
    __syncthreads();  // B6/B8: H2 half ready
    {
      q4w0[2] = *(const s16x8*)(qp0 + 64);
      q4w1[2] = *(const s16x8*)(qp1 + 64);
      q4w0[3] = *(const s16x8*)(qp0 + 96);
      q4w1[3] = *(const s16x8*)(qp1 + 96);
      s16x8 dc[2][2];
#pragma unroll
      for (int pf = 0; pf < 2; ++pf)
#pragma unroll
        for (int jt = 0; jt < 2; ++jt)
          dc[pf][jt] = *(const s16x8*)(smem + OFF_H2 + (jb + jt * 16 + lr) * PA +
                                       pf * 64 + lq * 16);
#pragma unroll
      for (int ks = 0; ks < 8; ++ks) {
        const int cur = ks & 1;
        s16x8 w0 = q4w0[ks & 3], w1 = q4w1[ks & 3];
        if (ks < 4) {
          q4w0[ks & 3] = *(const s16x8*)(qp0 + (ks + 4) * 32);
          q4w1[ks & 3] = *(const s16x8*)(qp1 + (ks + 4) * 32);
        }
        s16x8 d[2];
#pragma unroll
        for (int jt = 0; jt < 2; ++jt) d[jt] = dc[cur][jt];
        if (ks < 6) {
#pragma unroll
          for (int jt = 0; jt < 2; ++jt)
            dc[cur][jt] = *(const s16x8*)(smem + OFF_H2 + (jb + jt * 16 + lr) * PA +
                                          (ks + 2) * 64 + lq * 16);
        }
#pragma unroll
        for (int jt = 0; jt < 2; ++jt) {
          acc4[jt][0] = __builtin_amdgcn_mfma_f32_16x16x32_bf16(w0, d[jt], acc4[jt][0], 0, 0, 0);
          acc4[jt][1] = __builtin_amdgcn_mfma_f32_16x16x32_bf16(w1, d[jt], acc4[jt][1], 0, 0, 0);
        }
      }
    }
  }

  // ---- x2 = y + G4 + b2p; LN2 + edge mask + store ----
  f32x4 x2v[2][2];
#pragma unroll
  for (int nt = 0; nt < 2; ++nt) {
    const int n0 = nb2 + nt * 16 + lq * 4;
    f32x4 bv = *(const f32x4*)(b2p + n0);
#pragma unroll
    for (int jt = 0; jt < 2; ++jt) {
      const int j = jb + jt * 16 + lr;
      s16x4 yv = *(const s16x4*)(smem + OFF_Y + j * PY + n0 * 2);
      f32x4 yr;
#pragma unroll
      for (int v = 0; v < 4; ++v) yr[v] = bf2f(yv[v]);
      x2v[jt][nt] = acc4[jt][nt] + bv + yr;
    }
  }
  {
    float s[2], ss[2];
#pragma unroll
    for (int jt = 0; jt < 2; ++jt) {
      s[jt] = 0.f; ss[jt] = 0.f;
#pragma unroll
      for (int nt = 0; nt < 2; ++nt)
#pragma unroll
        for (int v = 0; v < 4; ++v) {
          const float x = x2v[jt][nt][v];
          s[jt] += x; ss[jt] += x * x;
        }
      s[jt] += __shfl_xor(s[jt], 16, 64);
      ss[jt] += __shfl_xor(ss[jt], 16, 64);
      s[jt] += __shfl_xor(s[jt], 32, 64);
      ss[jt] += __shfl_xor(ss[jt], 32, 64);
    }
    // SCR last read before B5 by all waves -> safe to overwrite
    if (lq == 0) {
#pragma unroll
      for (int jt = 0; jt < 2; ++jt) {
        const int j = jb + jt * 16 + lr;
        f32x2 p = {s[jt], ss[jt]};
        *(f32x2*)(smem + OFF_SCR + j * 32 + (wv & 3) * 8) = p;
      }
    }
    __syncthreads();  // B9
    float lnm[2], lnr[2], vp[2];
#pragma unroll
    for (int jt = 0; jt < 2; ++jt) {
      const int j = jb + jt * 16 + lr;
      f32x4 pA = *(const f32x4*)(smem + OFF_SCR + j * 32);
      f32x4 pB = *(const f32x4*)(smem + OFF_SCR + j * 32 + 16);
      const float S = pA[0] + pA[2] + pB[0] + pB[2];
      const float SS = pA[1] + pA[3] + pB[1] + pB[3];
      const float m = S * (1.f / 128.f);
      const float var = SS * (1.f / 128.f) - m * m;
      lnm[jt] = m;
      lnr[jt] = rsqrtf(var + 1e-5f);
      vp[jt] = (float)(jt ? em1 : em0);
    }
#pragma unroll
    for (int nt = 0; nt < 2; ++nt) {
      const int n0 = nb2 + nt * 16 + lq * 4;
      f32x4 gv = *(const f32x4*)(g2 + n0);
      f32x4 bv = *(const f32x4*)(be2 + n0);
#pragma unroll
      for (int jt = 0; jt < 2; ++jt) {
        const int j = jb + jt * 16 + lr;
        f32x4 o;
#pragma unroll
        for (int v = 0; v < 4; ++v)
          o[v] = ((x2v[jt][nt][v] - lnm[jt]) * lnr[jt] * gv[v] + bv[v]) * vp[jt];
        *(f32x4*)(out_pair + (rowbase + j) * 128 + n0) = o;
      }
    }
  }
}

// ---------------------------------------------------------------------------
extern "C" void kernel_launch(void* const* d_in, const int* in_sizes, int n_in,
                              void* d_out, int out_size, void* d_ws,
                              size_t ws_size, hipStream_t stream) {
  const float* node_h = (const float*)d_in[0];
  const float* pair_h = (const float*)d_in[1];
  const int* node_mask = (const int*)d_in[2];
  const int* edge_mask = (const int*)d_in[3];
  const float* nfp_W1 = (const float*)d_in[4];
  const float* nfp_b1 = (const float*)d_in[5];
  const float* nfp_W2 = (const float*)d_in[6];
  const float* nfp_b2 = (const float*)d_in[7];
  const float* pfn_W1 = (const float*)d_in[8];
  const float* pfn_b1 = (const float*)d_in[9];
  const float* pfn_W2 = (const float*)d_in[10];
  const float* pfn_b2 = (const float*)d_in[11];
  const float* nff_W1 = (const float*)d_in[12];
  const float* nff_b1 = (const float*)d_in[13];
  const float* nff_W2 = (const float*)d_in[14];
  const float* nff_b2 = (const float*)d_in[15];
  const float* pff_W1 = (const float*)d_in[16];
  const float* pff_b1 = (const float*)d_in[17];
  const float* pff_W2 = (const float*)d_in[18];
  const float* pff_b2 = (const float*)d_in[19];
  const float* og_W = (const float*)d_in[20];
  const float* og_b = (const float*)d_in[21];
  const float* ig_W = (const float*)d_in[22];
  const float* ig_b = (const float*)d_in[23];
  const float* nn1_g = (const float*)d_in[24];
  const float* nn1_b = (const float*)d_in[25];
  const float* nn2_g = (const float*)d_in[26];
  const float* nn2_b = (const float*)d_in[27];
  const float* pn1_g = (const float*)d_in[28];
  const float* pn1_b = (const float*)d_in[29];
  const float* pn2_g = (const float*)d_in[30];
  const float* pn2_b = (const float*)d_in[31];

  char* ws = (char*)d_ws;
  short* W1c = (short*)(ws);                 // 131072
  short* W2T = (short*)(ws + 131072);        // 65536
  short* W1Tp = (short*)(ws + 196608);       // 131072
  short* W2Tp = (short*)(ws + 327680);       // 131072
  float* Wu = (float*)(ws + 458752);         // 131072
  float* Whjv = (float*)(ws + 589824);       // 131072
  float* out_ctx = (float*)(ws + 720896);    // 524288
  float* in_ctx = (float*)(ws + 1245184);    // 524288
  short* node_bf = (short*)(ws + 1769472);   // 262144
  short* u_bf = (short*)(ws + 2031616);      // 524288
  short* hjv_bf = (short*)(ws + 2555904);    // 524288 -> 3080192

  // in-mode partial scratch: 64*256*128*2 = 4194304 + 64*256*4 = 65536
  const size_t scratch_need = 3080192ull + 4194304ull + 65536ull;
  short* pin;
  float* pdeg;
  if (ws_size >= scratch_need) {
    pin = (short*)(ws + 3080192);
    pdeg = (float*)(ws + 3080192 + 4194304);
  } else {
    // dead tail of out_pair: written here before pair_kernel overwrites it
    char* tail = (char*)d_out + (size_t)out_size * 4 - 4259840ull;
    pin = (short*)tail;
    pdeg = (float*)(tail + 4194304);
  }

  float* out_node = (float*)d_out;
  float* out_pair = (float*)d_out + 131072;

  prep_ctx_kernel<<<2240, 256, 0, stream>>>(
      pair_h, edge_mask, pfn_W1, pfn_W2, pff_W1, pff_W2, W1c, Wu, Whjv, W2T,
      W1Tp, W2Tp, out_ctx, pin, pdeg);
  inred_kernel<<<512, 256, 0, stream>>>(pin, pdeg, in_ctx);
  node_kernel<<<256, 256, 0, stream>>>(
      node_h, out_ctx, in_ctx, node_mask, og_W, og_b, ig_W, ig_b, nfp_W1,
      nfp_b1, nfp_W2, nfp_b2, nff_W1, nff_b1, nff_W2, nff_b2, nn1_g, nn1_b,
      nn2_g, nn2_b, Wu, pfn_b1, Whjv, out_node, node_bf, u_bf, hjv_bf);
  pair_kernel<<<4096, 512, 0, stream>>>(
      pair_h, node_bf, edge_mask, W1c, W2T, W1Tp, W2Tp, u_bf, hjv_bf, pfn_b2,
      pff_b1, pff_b2, pn1_g, pn1_b, pn2_g, pn2_b, out_pair);
}

// Round 13
// 573.331 us; speedup vs baseline: 1.0179x; 1.0179x over previous
//
#include <hip/hip_runtime.h>
#include <hip/hip_bf16.h>

#define DI __device__ __forceinline__

typedef float f32x4 __attribute__((ext_vector_type(4)));
typedef float f32x2 __attribute__((ext_vector_type(2)));
typedef short s16x8 __attribute__((ext_vector_type(8)));
typedef short s16x4 __attribute__((ext_vector_type(4)));
typedef unsigned u32x2 __attribute__((ext_vector_type(2)));
typedef unsigned u32x4 __attribute__((ext_vector_type(4)));

DI short f2bf(float x) {
  union { float f; unsigned u; } v; v.f = x;
  unsigned r = v.u + 0x7fffu + ((v.u >> 16) & 1u);
  return (short)(r >> 16);
}

DI float bf2f(short x) {
  union { unsigned u; float f; } v;
  v.u = ((unsigned)(unsigned short)x) << 16;
  return v.f;
}

DI unsigned cvt_pk(float lo, float hi) {  // low16 = bf16(lo), high16 = bf16(hi)
  unsigned r;
  asm("v_cvt_pk_bf16_f32 %0, %1, %2" : "=v"(r) : "v"(lo), "v"(hi));
  return r;
}

DI s16x8 pack8(f32x4 a, f32x4 b) {
  union { u32x4 u; s16x8 s; } r;
  r.u[0] = cvt_pk(a[0], a[1]); r.u[1] = cvt_pk(a[2], a[3]);
  r.u[2] = cvt_pk(b[0], b[1]); r.u[3] = cvt_pk(b[2], b[3]);
  return r.s;
}

// Fast gelu: x * sigmoid(1.5957691x + 0.0713548x^3)
DI float gelu_f(float x) {
  const float e = __expf(-x * fmaf(x * x, 0.0713548162f, 1.5957691216f));
  return __fdividef(x, 1.f + e);
}

// ---------------------------------------------------------------------------
// K1: fused prep (weights) + ctx.
//  blocks [0,1024): out-mode ctx (streamed; block owns (b,i), direct write)
//  blocks [1024,1280): in-mode streamed partials: block owns 4 i-rows
//    (256 blocks -> full CU coverage), 4 contiguous row-loads in flight,
//    writes bf16 partial sums + f32 partial degs per (chunk, j).
//  blocks [1280,2432): weight prep.
// ---------------------------------------------------------------------------
__global__ __launch_bounds__(256) void prep_ctx_kernel(
    const float* __restrict__ pair_h, const int* __restrict__ edge_mask,
    const float* __restrict__ pfnW1, const float* __restrict__ pfnW2,
    const float* __restrict__ pffW1, const float* __restrict__ pffW2,
    short* __restrict__ W1c, float* __restrict__ Wu, float* __restrict__ Whjv,
    short* __restrict__ W2T, short* __restrict__ W1Tp,
    short* __restrict__ W2Tp, float* __restrict__ out_ctx,
    short* __restrict__ pin, float* __restrict__ pdeg) {
  __shared__ float sacc[2][128];
  __shared__ float sdeg[2];
  const int t = threadIdx.x;
  if (blockIdx.x >= 1280) {  // ---- weight prep ----
    int idx = (blockIdx.x - 1280) * 256 + t;
    if (idx < 65536) {  // W1c [256 n][256 k] = [Wp | Wm]^T
      int n = idx / 256, k = idx % 256;
      float v = (k < 128) ? pfnW1[k * 256 + n] : pfnW1[(384 + k) * 256 + n];
      W1c[idx] = f2bf(v);
      return;
    }
    idx -= 65536;
    if (idx < 32768) {  // Wu f32 [128 k][256 n] = Whi + Wd
      int k = idx / 256, n = idx % 256;
      Wu[idx] = pfnW1[(128 + k) * 256 + n] + pfnW1[(384 + k) * 256 + n];
      return;
    }
    idx -= 32768;
    if (idx < 32768) {  // Whjv f32 [128 k][256 n] = Whj - Wd
      int k = idx / 256, n = idx % 256;
      Whjv[idx] = pfnW1[(256 + k) * 256 + n] - pfnW1[(384 + k) * 256 + n];
      return;
    }
    idx -= 32768;
    if (idx < 32768) {  // W2T [128 n][256 k]
      int n = idx / 256, k = idx % 256;
      W2T[idx] = f2bf(pfnW2[k * 128 + n]);
      return;
    }
    idx -= 32768;
    if (idx < 65536) {  // W1Tp [512 n][128 k]
      int n = idx / 128, k = idx % 128;
      W1Tp[idx] = f2bf(pffW1[k * 512 + n]);
      return;
    }
    idx -= 65536;
    if (idx < 65536) {  // W2Tp [128 n][512 k]
      int n = idx / 512, k = idx % 512;
      W2Tp[idx] = f2bf(pffW2[k * 128 + n]);
    }
    return;
  }
  if (blockIdx.x >= 1024) {  // ---- in-mode streamed partials (256 blocks) ----
    const int bx = blockIdx.x - 1024;   // 0..255
    const int b = bx >> 6, c = bx & 63; // chunk c: i in [c*4, c*4+4)
    const int i0 = c * 4;
    const int d4 = (t & 31) * 4;
    const int jrow = t >> 5;            // 0..7
    for (int jo = 0; jo < 32; ++jo) {
      const int j = jo * 8 + jrow;
      f32x4 acc = {0.f, 0.f, 0.f, 0.f};
      float dg = 0.f;
#pragma unroll
      for (int i = 0; i < 4; ++i) {
        const long row = (long)(b * 256 + i0 + i) * 256 + j;
        const float m = (float)edge_mask[row];
        f32x4 v = *(const f32x4*)(pair_h + row * 128 + d4);
#pragma unroll
        for (int e = 0; e < 4; ++e) acc[e] = fmaf(m, v[e], acc[e]);
        dg += m;
      }
      u32x2 pk = {cvt_pk(acc[0], acc[1]), cvt_pk(acc[2], acc[3])};
      *(u32x2*)(pin + ((long)bx * 256 + j) * 128 + d4) = pk;
      if ((t & 31) == 0) pdeg[bx * 256 + j] = dg;
    }
    return;
  }
  // ---- out-mode ctx (streamed; block owns i) ----
  const int wg = blockIdx.x;
  const int half = t >> 7, d = t & 127;
  const int b = wg >> 8, x = wg & 255;
  float acc = 0.f, deg = 0.f;
#pragma unroll 8
  for (int y0 = 0; y0 < 256; y0 += 2) {
    const int y = y0 + half;
    const long row = (long)(b * 256 + x) * 256 + y;
    const float m = (float)edge_mask[row];
    const float v = pair_h[row * 128 + d];
    acc = fmaf(m, v, acc);
    deg += m;
  }
  sacc[half][d] = acc;
  if (d == 0) sdeg[half] = deg;
  __syncthreads();
  if (t < 128) {
    float tot = sacc[0][d] + sacc[1][d];
    float dg = fmaxf(sdeg[0] + sdeg[1], 1.f);
    out_ctx[(b * 256 + x) * 128 + d] = tot / dg;
  }
}

// ---------------------------------------------------------------------------
// K1b: reduce in-mode partials (64 chunks) and divide by deg.
// ---------------------------------------------------------------------------
__global__ __launch_bounds__(256) void inred_kernel(
    const short* __restrict__ pin, const float* __restrict__ pdeg,
    float* __restrict__ in_ctx) {
  const int tid = blockIdx.x * 256 + threadIdx.x;  // 131072 total
  const int d = tid & 127;
  const int j = (tid >> 7) & 255;
  const int b = tid >> 15;
  float s = 0.f, dg = 0.f;
#pragma unroll 8
  for (int c = 0; c < 64; ++c) {
    const int bx = b * 64 + c;
    s += bf2f(pin[((long)bx * 256 + j) * 128 + d]);
    dg += pdeg[bx * 256 + j];
  }
  in_ctx[(b * 256 + j) * 128 + d] = s / fmaxf(dg, 1.f);
}

// ---------------------------------------------------------------------------
// K2: node path fp32 (unchanged from R11/R12).
// ---------------------------------------------------------------------------
__global__ __launch_bounds__(256) void node_kernel(
    const float* __restrict__ node_h, const float* __restrict__ out_ctx,
    const float* __restrict__ in_ctx, const int* __restrict__ node_mask,
    const float* __restrict__ ogW, const float* __restrict__ ogb,
    const float* __restrict__ igW, const float* __restrict__ igb,
    const float* __restrict__ nW1, const float* __restrict__ nb1,
    const float* __restrict__ nW2, const float* __restrict__ nb2,
    const float* __restrict__ fW1, const float* __restrict__ fb1,
    const float* __restrict__ fW2, const float* __restrict__ fb2,
    const float* __restrict__ g1, const float* __restrict__ be1,
    const float* __restrict__ g2, const float* __restrict__ be2,
    const float* __restrict__ Wu, const float* __restrict__ ub1,
    const float* __restrict__ Whjv, float* __restrict__ out_node,
    short* __restrict__ node_bf, short* __restrict__ u_bf,
    short* __restrict__ hjv_bf) {
  __shared__ float sh[4][896];
  __shared__ float fin[4][128];
  const int t = threadIdx.x;
  const int wv = t >> 6, lane = t & 63;
  float* const xn = sh[wv];
  float* const xo = sh[wv] + 128;
  float* const xi = sh[wv] + 256;
  float* const hh = sh[wv] + 384;
  const int row = blockIdx.x * 4 + wv;

#pragma unroll
  for (int c = 0; c < 2; ++c) {
    const int col = lane + 64 * c;
    xn[col] = node_h[row * 128 + col];
    xo[col] = out_ctx[row * 128 + col];
    xi[col] = in_ctx[row * 128 + col];
  }

  {
    float ao[2], ai[2];
#pragma unroll
    for (int c = 0; c < 2; ++c) {
      const int col = lane + 64 * c;
      ao[c] = ogb[col];
      ai[c] = igb[col];
    }
#pragma unroll 4
    for (int k = 0; k < 256; ++k) {
      float xov, xiv;
      if (k < 128) { xov = xiv = xn[k]; }
      else { xov = xo[k - 128]; xiv = xi[k - 128]; }
#pragma unroll
      for (int c = 0; c < 2; ++c) {
        const int col = lane + 64 * c;
        ao[c] += xov * ogW[k * 128 + col];
        ai[c] += xiv * igW[k * 128 + col];
      }
    }
#pragma unroll
    for (int c = 0; c < 2; ++c) {
      const int col = lane + 64 * c;
      const float go = 1.f / (1.f + __expf(-ao[c]));
      const float gi = 1.f / (1.f + __expf(-ai[c]));
      xo[col] *= go;
      xi[col] *= gi;
    }
  }

  {
    float a1[4];
#pragma unroll
    for (int c = 0; c < 4; ++c) a1[c] = nb1[lane + 64 * c];
#pragma unroll 4
    for (int k = 0; k < 384; ++k) {
      const float* src = (k < 128) ? xn : (k < 256) ? xo : xi;
      const float x = src[k & 127];
#pragma unroll
      for (int c = 0; c < 4; ++c) a1[c] += x * nW1[k * 256 + lane + 64 * c];
    }
#pragma unroll
    for (int c = 0; c < 4; ++c) hh[lane + 64 * c] = gelu_f(a1[c]);
  }
  {
    float a2[2];
#pragma unroll
    for (int c = 0; c < 2; ++c) a2[c] = nb2[lane + 64 * c];
#pragma unroll 4
    for (int k = 0; k < 256; ++k) {
      const float h = hh[k];
#pragma unroll
      for (int c = 0; c < 2; ++c) a2[c] += h * nW2[k * 128 + lane + 64 * c];
    }
    float v0 = xn[lane] + a2[0];
    float v1 = xn[lane + 64] + a2[1];
    float s = v0 + v1, ss = v0 * v0 + v1 * v1;
#pragma unroll
    for (int off = 1; off < 64; off <<= 1) {
      s += __shfl_xor(s, off, 64);
      ss += __shfl_xor(ss, off, 64);
    }
    const float m = s * (1.f / 128.f);
    const float var = ss * (1.f / 128.f) - m * m;
    const float rs = rsqrtf(var + 1e-5f);
    xn[lane] = (v0 - m) * rs * g1[lane] + be1[lane];
    xn[lane + 64] = (v1 - m) * rs * g1[lane + 64] + be1[lane + 64];
  }

  {
    float af[8];
#pragma unroll
    for (int c = 0; c < 8; ++c) af[c] = fb1[lane + 64 * c];
#pragma unroll 4
    for (int k = 0; k < 128; ++k) {
      const float x = xn[k];
#pragma unroll
      for (int c = 0; c < 8; ++c) af[c] += x * fW1[k * 512 + lane + 64 * c];
    }
#pragma unroll
    for (int c = 0; c < 8; ++c) hh[lane + 64 * c] = gelu_f(af[c]);
  }
  {
    float a2[2];
#pragma unroll
    for (int c = 0; c < 2; ++c) a2[c] = fb2[lane + 64 * c];
#pragma unroll 4
    for (int k = 0; k < 512; ++k) {
      const float h = hh[k];
#pragma unroll
      for (int c = 0; c < 2; ++c) a2[c] += h * fW2[k * 128 + lane + 64 * c];
    }
    float v0 = xn[lane] + a2[0];
    float v1 = xn[lane + 64] + a2[1];
    float s = v0 + v1, ss = v0 * v0 + v1 * v1;
#pragma unroll
    for (int off = 1; off < 64; off <<= 1) {
      s += __shfl_xor(s, off, 64);
      ss += __shfl_xor(ss, off, 64);
    }
    const float m = s * (1.f / 128.f);
    const float var = ss * (1.f / 128.f) - m * m;
    const float rs = rsqrtf(var + 1e-5f);
    const float msk = (float)node_mask[row];
    const float o0 = ((v0 - m) * rs * g2[lane] + be2[lane]) * msk;
    const float o1 = ((v1 - m) * rs * g2[lane + 64] + be2[lane + 64]) * msk;
    out_node[row * 128 + lane] = o0;
    out_node[row * 128 + lane + 64] = o1;
    node_bf[row * 128 + lane] = f2bf(o0);
    node_bf[row * 128 + lane + 64] = f2bf(o1);
    fin[wv][lane] = o0;
    fin[wv][lane + 64] = o1;
  }
  __syncthreads();
  {
    float uacc[4], hacc[4];
    const float bb = ub1[t];
#pragma unroll
    for (int r = 0; r < 4; ++r) { uacc[r] = bb; hacc[r] = 0.f; }
#pragma unroll 4
    for (int k = 0; k < 128; ++k) {
      const float wu = Wu[k * 256 + t];
      const float wh = Whjv[k * 256 + t];
#pragma unroll
      for (int r = 0; r < 4; ++r) {
        uacc[r] += fin[r][k] * wu;
        hacc[r] += fin[r][k] * wh;
      }
    }
#pragma unroll
    for (int r = 0; r < 4; ++r) {
      u_bf[(blockIdx.x * 4 + r) * 256 + t] = f2bf(uacc[r]);
      hjv_bf[(blockIdx.x * 4 + r) * 256 + t] = f2bf(hacc[r]);
    }
  }
}

// ---------------------------------------------------------------------------
// K3: fused pair kernel (UNCHANGED — verified ~435us).
// ---------------------------------------------------------------------------
__global__ __launch_bounds__(512, 4) void pair_kernel(
    const float* __restrict__ pair_h, const short* __restrict__ node_bf,
    const int* __restrict__ edge_mask, const short* __restrict__ W1c,
    const short* __restrict__ W2T, const short* __restrict__ W1Tp,
    const short* __restrict__ W2Tp, const short* __restrict__ u_bf,
    const short* __restrict__ hjv_bf, const float* __restrict__ b2,
    const float* __restrict__ b1p, const float* __restrict__ b2p,
    const float* __restrict__ g1, const float* __restrict__ be1,
    const float* __restrict__ g2, const float* __restrict__ be2,
    float* __restrict__ out_pair) {
  constexpr int OFF_A = 0, OFF_H1 = 0, OFF_Y = 0, OFF_H2 = 33792,
                OFF_SCR = 67584;
  constexpr int PA = 528, PY = 272;  // byte pitches
  __shared__ __align__(16) char smem[69632];

  const int t = threadIdx.x;
  const int wg = blockIdx.x;
  const int b = wg >> 10, rem = wg & 1023;
  const int i = rem >> 2, j0 = (rem & 3) << 6;
  const int bi = (b << 8) + i;
  const long rowbase = (long)bi * 256 + j0;

  const int lane = t & 63, wv = t >> 6;
  const int lr = lane & 15, lq = lane >> 4;
  const int jb = (wv >> 2) * 32, nb2 = (wv & 3) * 32;

  // ---- P0: build A = [pair | hi*hj] bf16, padded pitch ----
  {
    const int r = t >> 3, oc = t & 7, c0 = oc * 16;
    const float* prow = pair_h + (rowbase + r) * 128 + c0;
    const short* hjrow = node_bf + (b * 256 + j0 + r) * 128 + c0;
    const short* hirow = node_bf + (b * 256 + i) * 128 + c0;
    char* arow = smem + OFF_A + r * PA;
#pragma unroll
    for (int h = 0; h < 2; ++h) {
      f32x4 p0 = *(const f32x4*)(prow + h * 8);
      f32x4 p1 = *(const f32x4*)(prow + h * 8 + 4);
      s16x8 hj = *(const s16x8*)(hjrow + h * 8);
      s16x8 hi = *(const s16x8*)(hirow + h * 8);
      *(s16x8*)(arow + c0 * 2 + h * 16) = pack8(p0, p1);
      union { u32x4 u; s16x8 s; } pd;
#pragma unroll
      for (int e = 0; e < 4; ++e)
        pd.u[e] = cvt_pk(bf2f(hi[2 * e]) * bf2f(hj[2 * e]),
                         bf2f(hi[2 * e + 1]) * bf2f(hj[2 * e + 1]));
      *(s16x8*)(arow + 256 + c0 * 2 + h * 16) = pd.s;
    }
  }
  __syncthreads();  // B1: A ready

  // ---- GEMM1: C1^T[n][j] over K=256; 4-deep w prefetch, 2-deep d roll ----
  f32x4 acc1[4][2];
#pragma unroll
  for (int jt = 0; jt < 4; ++jt)
#pragma unroll
    for (int nt = 0; nt < 2; ++nt) acc1[jt][nt] = {0.f, 0.f, 0.f, 0.f};
  {
    const int nb = wv * 32;
    const short* wp0 = W1c + (nb + lr) * 256 + lq * 8;
    const short* wp1 = W1c + (nb + 16 + lr) * 256 + lq * 8;
    s16x8 w0p[4], w1p[4];
#pragma unroll
    for (int pf = 0; pf < 4; ++pf) {
      w0p[pf] = *(const s16x8*)(wp0 + pf * 32);
      w1p[pf] = *(const s16x8*)(wp1 + pf * 32);
    }
    s16x8 dc[2][4];
#pragma unroll
    for (int pf = 0; pf < 2; ++pf)
#pragma unroll
      for (int jt = 0; jt < 4; ++jt)
        dc[pf][jt] = *(const s16x8*)(smem + OFF_A + (jt * 16 + lr) * PA +
                                     pf * 64 + lq * 16);
#pragma unroll
    for (int ks = 0; ks < 8; ++ks) {
      const int cur = ks & 1;
      s16x8 w0 = w0p[ks & 3], w1 = w1p[ks & 3];
      if (ks < 4) {
        w0p[ks & 3] = *(const s16x8*)(wp0 + (ks + 4) * 32);
        w1p[ks & 3] = *(const s16x8*)(wp1 + (ks + 4) * 32);
      }
      s16x8 d[4];
#pragma unroll
      for (int jt = 0; jt < 4; ++jt) d[jt] = dc[cur][jt];
      if (ks < 6) {
#pragma unroll
        for (int jt = 0; jt < 4; ++jt)
          dc[cur][jt] = *(const s16x8*)(smem + OFF_A + (jt * 16 + lr) * PA +
                                        (ks + 2) * 64 + lq * 16);
      }
#pragma unroll
      for (int jt = 0; jt < 4; ++jt) {
        acc1[jt][0] = __builtin_amdgcn_mfma_f32_16x16x32_bf16(w0, d[jt], acc1[jt][0], 0, 0, 0);
        acc1[jt][1] = __builtin_amdgcn_mfma_f32_16x16x32_bf16(w1, d[jt], acc1[jt][1], 0, 0, 0);
      }
    }
  }
  // pre-issue: u (H1 epilogue) + G2 first weights -- in flight across barrier
  s16x4 uv0 = *(const s16x4*)(u_bf + bi * 256 + wv * 32 + lq * 4);
  s16x4 uv1 = *(const s16x4*)(u_bf + bi * 256 + wv * 32 + 16 + lq * 4);
  const short* q2p0 = W2T + (nb2 + lr) * 256 + lq * 8;
  const short* q2p1 = W2T + (nb2 + 16 + lr) * 256 + lq * 8;
  s16x8 q2w0[4], q2w1[4];
  q2w0[0] = *(const s16x8*)q2p0;
  q2w1[0] = *(const s16x8*)q2p1;
  q2w0[1] = *(const s16x8*)(q2p0 + 32);
  q2w1[1] = *(const s16x8*)(q2p1 + 32);
  __syncthreads();  // B2: A reads done -> H1 overlay
  {
    const int nb = wv * 32;
#pragma unroll
    for (int nt = 0; nt < 2; ++nt) {
      const int n0 = nb + nt * 16 + lq * 4;
      const s16x4 uv = nt ? uv1 : uv0;
      f32x4 uu;
#pragma unroll
      for (int v = 0; v < 4; ++v) uu[v] = bf2f(uv[v]);  // u includes b1
#pragma unroll
      for (int jt = 0; jt < 4; ++jt) {
        const int j = jt * 16 + lr;
        s16x4 hv = *(const s16x4*)(hjv_bf + (b * 256 + j0 + j) * 256 + n0);
        float pre[4];
#pragma unroll
        for (int v = 0; v < 4; ++v)
          pre[v] = acc1[jt][nt][v] + uu[v] + bf2f(hv[v]);
        u32x2 pk = {cvt_pk(gelu_f(pre[0]), gelu_f(pre[1])),
                    cvt_pk(gelu_f(pre[2]), gelu_f(pre[3]))};
        *(u32x2*)(smem + OFF_H1 + j * PA + n0 * 2) = pk;
      }
    }
  }
  __syncthreads();  // B3: H1 ready

  // ---- GEMM2: x1^T[n][j] over K=256; wave -> (jb, nb2) 32x32 ----
  f32x4 x1v[2][2];
  {
    q2w0[2] = *(const s16x8*)(q2p0 + 64);
    q2w1[2] = *(const s16x8*)(q2p1 + 64);
    q2w0[3] = *(const s16x8*)(q2p0 + 96);
    q2w1[3] = *(const s16x8*)(q2p1 + 96);
    f32x4 pr[2][2];
#pragma unroll
    for (int nt = 0; nt < 2; ++nt)
#pragma unroll
      for (int jt = 0; jt < 2; ++jt)
        pr[jt][nt] = *(const f32x4*)(pair_h + (rowbase + jb + jt * 16 + lr) * 128 +
                                     nb2 + nt * 16 + lq * 4);
    s16x8 dc[2][2];
#pragma unroll
    for (int pf = 0; pf < 2; ++pf)
#pragma unroll
      for (int jt = 0; jt < 2; ++jt)
        dc[pf][jt] = *(const s16x8*)(smem + OFF_H1 + (jb + jt * 16 + lr) * PA +
                                     pf * 64 + lq * 16);
    f32x4 acc2[2][2];
#pragma unroll
    for (int jt = 0; jt < 2; ++jt)
#pragma unroll
      for (int nt = 0; nt < 2; ++nt) acc2[jt][nt] = {0.f, 0.f, 0.f, 0.f};
#pragma unroll
    for (int ks = 0; ks < 8; ++ks) {
      const int cur = ks & 1;
      s16x8 w0 = q2w0[ks & 3], w1 = q2w1[ks & 3];
      if (ks < 4) {
        q2w0[ks & 3] = *(const s16x8*)(q2p0 + (ks + 4) * 32);
        q2w1[ks & 3] = *(const s16x8*)(q2p1 + (ks + 4) * 32);
      }
      s16x8 d[2];
#pragma unroll
      for (int jt = 0; jt < 2; ++jt) d[jt] = dc[cur][jt];
      if (ks < 6) {
#pragma unroll
        for (int jt = 0; jt < 2; ++jt)
          dc[cur][jt] = *(const s16x8*)(smem + OFF_H1 + (jb + jt * 16 + lr) * PA +
                                        (ks + 2) * 64 + lq * 16);
      }
#pragma unroll
      for (int jt = 0; jt < 2; ++jt) {
        acc2[jt][0] = __builtin_amdgcn_mfma_f32_16x16x32_bf16(w0, d[jt], acc2[jt][0], 0, 0, 0);
        acc2[jt][1] = __builtin_amdgcn_mfma_f32_16x16x32_bf16(w1, d[jt], acc2[jt][1], 0, 0, 0);
      }
    }
#pragma unroll
    for (int nt = 0; nt < 2; ++nt) {
      const int n0 = nb2 + nt * 16 + lq * 4;
      f32x4 bv = *(const f32x4*)(b2 + n0);
#pragma unroll
      for (int jt = 0; jt < 2; ++jt)
        x1v[jt][nt] = acc2[jt][nt] + bv + pr[jt][nt];
    }
  }
  // ---- LN1 in-reg ----
  {
    float s[2], ss[2];
#pragma unroll
    for (int jt = 0; jt < 2; ++jt) {
      s[jt] = 0.f; ss[jt] = 0.f;
#pragma unroll
      for (int nt = 0; nt < 2; ++nt)
#pragma unroll
        for (int v = 0; v < 4; ++v) {
          const float x = x1v[jt][nt][v];
          s[jt] += x; ss[jt] += x * x;
        }
      s[jt] += __shfl_xor(s[jt], 16, 64);
      ss[jt] += __shfl_xor(ss[jt], 16, 64);
      s[jt] += __shfl_xor(s[jt], 32, 64);
      ss[jt] += __shfl_xor(ss[jt], 32, 64);
    }
    if (lq == 0) {
#pragma unroll
      for (int jt = 0; jt < 2; ++jt) {
        const int j = jb + jt * 16 + lr;
        f32x2 p = {s[jt], ss[jt]};
        *(f32x2*)(smem + OFF_SCR + j * 32 + (wv & 3) * 8) = p;
      }
    }
    __syncthreads();  // B4: H1 reads done + SCR partials visible
    float lnm[2], lnr[2];
#pragma unroll
    for (int jt = 0; jt < 2; ++jt) {
      const int j = jb + jt * 16 + lr;
      f32x4 pA = *(const f32x4*)(smem + OFF_SCR + j * 32);
      f32x4 pB = *(const f32x4*)(smem + OFF_SCR + j * 32 + 16);
      const float S = pA[0] + pA[2] + pB[0] + pB[2];
      const float SS = pA[1] + pA[3] + pB[1] + pB[3];
      const float m = S * (1.f / 128.f);
      const float var = SS * (1.f / 128.f) - m * m;
      lnm[jt] = m;
      lnr[jt] = rsqrtf(var + 1e-5f);
    }
#pragma unroll
    for (int nt = 0; nt < 2; ++nt) {
      const int n0 = nb2 + nt * 16 + lq * 4;
      f32x4 gv = *(const f32x4*)(g1 + n0);
      f32x4 bv = *(const f32x4*)(be1 + n0);
#pragma unroll
      for (int jt = 0; jt < 2; ++jt) {
        const int j = jb + jt * 16 + lr;
        float y[4];
#pragma unroll
        for (int v = 0; v < 4; ++v)
          y[v] = (x1v[jt][nt][v] - lnm[jt]) * lnr[jt] * gv[v] + bv[v];
        u32x2 pk = {cvt_pk(y[0], y[1]), cvt_pk(y[2], y[3])};
        *(u32x2*)(smem + OFF_Y + j * PY + n0 * 2) = pk;
      }
    }
  }
  // pre-issue G3-p0 first weights + edge_mask before the barrier
  const short* g3p0a = W1Tp + (wv * 32 + lr) * 128 + lq * 8;
  const short* g3p1a = W1Tp + (wv * 32 + 16 + lr) * 128 + lq * 8;
  s16x8 g3w0[4], g3w1[4];
  g3w0[0] = *(const s16x8*)g3p0a;
  g3w1[0] = *(const s16x8*)g3p1a;
  g3w0[1] = *(const s16x8*)(g3p0a + 32);
  g3w1[1] = *(const s16x8*)(g3p1a + 32);
  const int em0 = edge_mask[rowbase + jb + lr];
  const int em1 = edge_mask[rowbase + jb + 16 + lr];
  __syncthreads();  // B5: Y ready

  // ---- pff: 2 K-halves; per half GEMM3(K=128)->H2half, GEMM4 accumulates ----
  f32x4 acc4[2][2];
#pragma unroll
  for (int jt = 0; jt < 2; ++jt)
#pragma unroll
    for (int nt = 0; nt < 2; ++nt) acc4[jt][nt] = {0.f, 0.f, 0.f, 0.f};

#pragma unroll
  for (int p = 0; p < 2; ++p) {
    f32x4 acc3[4][2];
#pragma unroll
    for (int jt = 0; jt < 4; ++jt)
#pragma unroll
      for (int nt = 0; nt < 2; ++nt) acc3[jt][nt] = {0.f, 0.f, 0.f, 0.f};
    {
      const int nb3 = p * 256 + wv * 32;
      const short* wp0 = W1Tp + (nb3 + lr) * 128 + lq * 8;
      const short* wp1 = W1Tp + (nb3 + 16 + lr) * 128 + lq * 8;
      if (p == 0) {  // slots 0,1 pre-issued before barrier B5
        g3w0[2] = *(const s16x8*)(wp0 + 64);
        g3w1[2] = *(const s16x8*)(wp1 + 64);
        g3w0[3] = *(const s16x8*)(wp0 + 96);
        g3w1[3] = *(const s16x8*)(wp1 + 96);
      } else {
#pragma unroll
        for (int pf = 0; pf < 4; ++pf) {
          g3w0[pf] = *(const s16x8*)(wp0 + pf * 32);
          g3w1[pf] = *(const s16x8*)(wp1 + pf * 32);
        }
      }
#pragma unroll
      for (int ks = 0; ks < 4; ++ks) {
        s16x8 d[4];
#pragma unroll
        for (int jt = 0; jt < 4; ++jt)
          d[jt] = *(const s16x8*)(smem + OFF_Y + (jt * 16 + lr) * PY +
                                  ks * 64 + lq * 16);
#pragma unroll
        for (int jt = 0; jt < 4; ++jt) {
          acc3[jt][0] = __builtin_amdgcn_mfma_f32_16x16x32_bf16(g3w0[ks], d[jt], acc3[jt][0], 0, 0, 0);
          acc3[jt][1] = __builtin_amdgcn_mfma_f32_16x16x32_bf16(g3w1[ks], d[jt], acc3[jt][1], 0, 0, 0);
        }
      }
    }
    // pre-issue G4 weights for this half (in flight across H2-write + barrier)
    const short* qp0 = W2Tp + (nb2 + lr) * 512 + p * 256 + lq * 8;
    const short* qp1 = W2Tp + (nb2 + 16 + lr) * 512 + p * 256 + lq * 8;
    s16x8 q4w0[4], q4w1[4];
    q4w0[0] = *(const s16x8*)qp0;
    q4w1[0] = *(const s16x8*)qp1;
    q4w0[1] = *(const s16x8*)(qp0 + 32);
    q4w1[1] = *(const s16x8*)(qp1 + 32);
    if (p == 1) __syncthreads();  // B7: G4-p0 H2 reads done before overwrite
    {
#pragma unroll
      for (int nt = 0; nt < 2; ++nt) {
        const int n0l = wv * 32 + nt * 16 + lq * 4;  // local n within half
        f32x4 bv = *(const f32x4*)(b1p + p * 256 + n0l);
#pragma unroll
        for (int jt = 0; jt < 4; ++jt) {
          const int j = jt * 16 + lr;
          u32x2 pk = {cvt_pk(gelu_f(acc3[jt][nt][0] + bv[0]),
                             gelu_f(acc3[jt][nt][1] + bv[1])),
                      cvt_pk(gelu_f(acc3[jt][nt][2] + bv[2]),
                             gelu_f(acc3[jt][nt][3] + bv[3]))};
          *(u32x2*)(smem + OFF_H2 + j * PA + n0l * 2) = pk;
        }
      }
    }
    __syncthreads();  // B6/B8: H2 half ready
    {
      q4w0[2] = *(const s16x8*)(qp0 + 64);
      q4w1[2] = *(const s16x8*)(qp1 + 64);
      q4w0[3] = *(const s16x8*)(qp0 + 96);
      q4w1[3] = *(const s16x8*)(qp1 + 96);
      s16x8 dc[2][2];
#pragma unroll
      for (int pf = 0; pf < 2; ++pf)
#pragma unroll
        for (int jt = 0; jt < 2; ++jt)
          dc[pf][jt] = *(const s16x8*)(smem + OFF_H2 + (jb + jt * 16 + lr) * PA +
                                       pf * 64 + lq * 16);
#pragma unroll
      for (int ks = 0; ks < 8; ++ks) {
        const int cur = ks & 1;
        s16x8 w0 = q4w0[ks & 3], w1 = q4w1[ks & 3];
        if (ks < 4) {
          q4w0[ks & 3] = *(const s16x8*)(qp0 + (ks + 4) * 32);
          q4w1[ks & 3] = *(const s16x8*)(qp1 + (ks + 4) * 32);
        }
        s16x8 d[2];
#pragma unroll
        for (int jt = 0; jt < 2; ++jt) d[jt] = dc[cur][jt];
        if (ks < 6) {
#pragma unroll
          for (int jt = 0; jt < 2; ++jt)
            dc[cur][jt] = *(const s16x8*)(smem + OFF_H2 + (jb + jt * 16 + lr) * PA +
                                          (ks + 2) * 64 + lq * 16);
        }
#pragma unroll
        for (int jt = 0; jt < 2; ++jt) {
          acc4[jt][0] = __builtin_amdgcn_mfma_f32_16x16x32_bf16(w0, d[jt], acc4[jt][0], 0, 0, 0);
          acc4[jt][1] = __builtin_amdgcn_mfma_f32_16x16x32_bf16(w1, d[jt], acc4[jt][1], 0, 0, 0);
        }
      }
    }
  }

  // ---- x2 = y + G4 + b2p; LN2 + edge mask + store ----
  f32x4 x2v[2][2];
#pragma unroll
  for (int nt = 0; nt < 2; ++nt) {
    const int n0 = nb2 + nt * 16 + lq * 4;
    f32x4 bv = *(const f32x4*)(b2p + n0);
#pragma unroll
    for (int jt = 0; jt < 2; ++jt) {
      const int j = jb + jt * 16 + lr;
      s16x4 yv = *(const s16x4*)(smem + OFF_Y + j * PY + n0 * 2);
      f32x4 yr;
#pragma unroll
      for (int v = 0; v < 4; ++v) yr[v] = bf2f(yv[v]);
      x2v[jt][nt] = acc4[jt][nt] + bv + yr;
    }
  }
  {
    float s[2], ss[2];
#pragma unroll
    for (int jt = 0; jt < 2; ++jt) {
      s[jt] = 0.f; ss[jt] = 0.f;
#pragma unroll
      for (int nt = 0; nt < 2; ++nt)
#pragma unroll
        for (int v = 0; v < 4; ++v) {
          const float x = x2v[jt][nt][v];
          s[jt] += x; ss[jt] += x * x;
        }
      s[jt] += __shfl_xor(s[jt], 16, 64);
      ss[jt] += __shfl_xor(ss[jt], 16, 64);
      s[jt] += __shfl_xor(s[jt], 32, 64);
      ss[jt] += __shfl_xor(ss[jt], 32, 64);
    }
    // SCR last read before B5 by all waves -> safe to overwrite
    if (lq == 0) {
#pragma unroll
      for (int jt = 0; jt < 2; ++jt) {
        const int j = jb + jt * 16 + lr;
        f32x2 p = {s[jt], ss[jt]};
        *(f32x2*)(smem + OFF_SCR + j * 32 + (wv & 3) * 8) = p;
      }
    }
    __syncthreads();  // B9
    float lnm[2], lnr[2], vp[2];
#pragma unroll
    for (int jt = 0; jt < 2; ++jt) {
      const int j = jb + jt * 16 + lr;
      f32x4 pA = *(const f32x4*)(smem + OFF_SCR + j * 32);
      f32x4 pB = *(const f32x4*)(smem + OFF_SCR + j * 32 + 16);
      const float S = pA[0] + pA[2] + pB[0] + pB[2];
      const float SS = pA[1] + pA[3] + pB[1] + pB[3];
      const float m = S * (1.f / 128.f);
      const float var = SS * (1.f / 128.f) - m * m;
      lnm[jt] = m;
      lnr[jt] = rsqrtf(var + 1e-5f);
      vp[jt] = (float)(jt ? em1 : em0);
    }
#pragma unroll
    for (int nt = 0; nt < 2; ++nt) {
      const int n0 = nb2 + nt * 16 + lq * 4;
      f32x4 gv = *(const f32x4*)(g2 + n0);
      f32x4 bv = *(const f32x4*)(be2 + n0);
#pragma unroll
      for (int jt = 0; jt < 2; ++jt) {
        const int j = jb + jt * 16 + lr;
        f32x4 o;
#pragma unroll
        for (int v = 0; v < 4; ++v)
          o[v] = ((x2v[jt][nt][v] - lnm[jt]) * lnr[jt] * gv[v] + bv[v]) * vp[jt];
        *(f32x4*)(out_pair + (rowbase + j) * 128 + n0) = o;
      }
    }
  }
}

// ---------------------------------------------------------------------------
extern "C" void kernel_launch(void* const* d_in, const int* in_sizes, int n_in,
                              void* d_out, int out_size, void* d_ws,
                              size_t ws_size, hipStream_t stream) {
  const float* node_h = (const float*)d_in[0];
  const float* pair_h = (const float*)d_in[1];
  const int* node_mask = (const int*)d_in[2];
  const int* edge_mask = (const int*)d_in[3];
  const float* nfp_W1 = (const float*)d_in[4];
  const float* nfp_b1 = (const float*)d_in[5];
  const float* nfp_W2 = (const float*)d_in[6];
  const float* nfp_b2 = (const float*)d_in[7];
  const float* pfn_W1 = (const float*)d_in[8];
  const float* pfn_b1 = (const float*)d_in[9];
  const float* pfn_W2 = (const float*)d_in[10];
  const float* pfn_b2 = (const float*)d_in[11];
  const float* nff_W1 = (const float*)d_in[12];
  const float* nff_b1 = (const float*)d_in[13];
  const float* nff_W2 = (const float*)d_in[14];
  const float* nff_b2 = (const float*)d_in[15];
  const float* pff_W1 = (const float*)d_in[16];
  const float* pff_b1 = (const float*)d_in[17];
  const float* pff_W2 = (const float*)d_in[18];
  const float* pff_b2 = (const float*)d_in[19];
  const float* og_W = (const float*)d_in[20];
  const float* og_b = (const float*)d_in[21];
  const float* ig_W = (const float*)d_in[22];
  const float* ig_b = (const float*)d_in[23];
  const float* nn1_g = (const float*)d_in[24];
  const float* nn1_b = (const float*)d_in[25];
  const float* nn2_g = (const float*)d_in[26];
  const float* nn2_b = (const float*)d_in[27];
  const float* pn1_g = (const float*)d_in[28];
  const float* pn1_b = (const float*)d_in[29];
  const float* pn2_g = (const float*)d_in[30];
  const float* pn2_b = (const float*)d_in[31];

  char* ws = (char*)d_ws;
  short* W1c = (short*)(ws);                 // 131072
  short* W2T = (short*)(ws + 131072);        // 65536
  short* W1Tp = (short*)(ws + 196608);       // 131072
  short* W2Tp = (short*)(ws + 327680);       // 131072
  float* Wu = (float*)(ws + 458752);         // 131072
  float* Whjv = (float*)(ws + 589824);       // 131072
  float* out_ctx = (float*)(ws + 720896);    // 524288
  float* in_ctx = (float*)(ws + 1245184);    // 524288
  short* node_bf = (short*)(ws + 1769472);   // 262144
  short* u_bf = (short*)(ws + 2031616);      // 524288
  short* hjv_bf = (short*)(ws + 2555904);    // 524288 -> 3080192

  // in-mode partial scratch: 256*256*128*2 = 16777216 + 256*256*4 = 262144
  const size_t scratch_need = 3080192ull + 16777216ull + 262144ull;
  short* pin;
  float* pdeg;
  if (ws_size >= scratch_need) {
    pin = (short*)(ws + 3080192);
    pdeg = (float*)(ws + 3080192 + 16777216);
  } else {
    // dead tail of out_pair: written before pair_kernel overwrites it
    char* tail = (char*)d_out + (size_t)out_size * 4 - 17039360ull;
    pin = (short*)tail;
    pdeg = (float*)(tail + 16777216);
  }

  float* out_node = (float*)d_out;
  float* out_pair = (float*)d_out + 131072;

  prep_ctx_kernel<<<2432, 256, 0, stream>>>(
      pair_h, edge_mask, pfn_W1, pfn_W2, pff_W1, pff_W2, W1c, Wu, Whjv, W2T,
      W1Tp, W2Tp, out_ctx, pin, pdeg);
  inred_kernel<<<512, 256, 0, stream>>>(pin, pdeg, in_ctx);
  node_kernel<<<256, 256, 0, stream>>>(
      node_h, out_ctx, in_ctx, node_mask, og_W, og_b, ig_W, ig_b, nfp_W1,
      nfp_b1, nfp_W2, nfp_b2, nff_W1, nff_b1, nff_W2, nff_b2, nn1_g, nn1_b,
      nn2_g, nn2_b, Wu, pfn_b1, Whjv, out_node, node_bf, u_bf, hjv_bf);
  pair_kernel<<<4096, 512, 0, stream>>>(
      pair_h, node_bf, edge_mask, W1c, W2T, W1Tp, W2Tp, u_bf, hjv_bf, pfn_b2,
      pff_b1, pff_b2, pn1_g, pn1_b, pn2_g, pn2_b, out_pair);
}

// Round 14
// 562.935 us; speedup vs baseline: 1.0367x; 1.0185x over previous
//
#include <hip/hip_runtime.h>
#include <hip/hip_bf16.h>

#define DI __device__ __forceinline__

typedef float f32x4 __attribute__((ext_vector_type(4)));
typedef float f32x2 __attribute__((ext_vector_type(2)));
typedef short s16x8 __attribute__((ext_vector_type(8)));
typedef short s16x4 __attribute__((ext_vector_type(4)));
typedef unsigned u32x2 __attribute__((ext_vector_type(2)));
typedef unsigned u32x4 __attribute__((ext_vector_type(4)));

DI short f2bf(float x) {
  union { float f; unsigned u; } v; v.f = x;
  unsigned r = v.u + 0x7fffu + ((v.u >> 16) & 1u);
  return (short)(r >> 16);
}

DI float bf2f(short x) {
  union { unsigned u; float f; } v;
  v.u = ((unsigned)(unsigned short)x) << 16;
  return v.f;
}

DI unsigned cvt_pk(float lo, float hi) {  // low16 = bf16(lo), high16 = bf16(hi)
  unsigned r;
  asm("v_cvt_pk_bf16_f32 %0, %1, %2" : "=v"(r) : "v"(lo), "v"(hi));
  return r;
}

DI s16x8 pack8(f32x4 a, f32x4 b) {
  union { u32x4 u; s16x8 s; } r;
  r.u[0] = cvt_pk(a[0], a[1]); r.u[1] = cvt_pk(a[2], a[3]);
  r.u[2] = cvt_pk(b[0], b[1]); r.u[3] = cvt_pk(b[2], b[3]);
  return r.s;
}

// Fast gelu: x * sigmoid(1.5957691x + 0.0713548x^3)
DI float gelu_f(float x) {
  const float e = __expf(-x * fmaf(x * x, 0.0713548162f, 1.5957691216f));
  return __fdividef(x, 1.f + e);
}

// ---------------------------------------------------------------------------
// K1: fused prep (weights) + ctx reductions (branch-free, unroll 8).
// R14 = R10 exact (best measured total 564us).
// ---------------------------------------------------------------------------
__global__ __launch_bounds__(256) void prep_ctx_kernel(
    const float* __restrict__ pair_h, const int* __restrict__ edge_mask,
    const float* __restrict__ pfnW1, const float* __restrict__ pfnW2,
    const float* __restrict__ pffW1, const float* __restrict__ pffW2,
    short* __restrict__ W1c, float* __restrict__ Wu, float* __restrict__ Whjv,
    short* __restrict__ W2T, short* __restrict__ W1Tp,
    short* __restrict__ W2Tp, float* __restrict__ out_ctx,
    float* __restrict__ in_ctx) {
  __shared__ float sacc[2][128];
  __shared__ float sdeg[2];
  const int t = threadIdx.x;
  if (blockIdx.x >= 2048) {
    int idx = (blockIdx.x - 2048) * 256 + t;
    if (idx < 65536) {  // W1c [256 n][256 k] = [Wp | Wm]^T
      int n = idx / 256, k = idx % 256;
      float v = (k < 128) ? pfnW1[k * 256 + n] : pfnW1[(384 + k) * 256 + n];
      W1c[idx] = f2bf(v);
      return;
    }
    idx -= 65536;
    if (idx < 32768) {  // Wu f32 [128 k][256 n] = Whi + Wd
      int k = idx / 256, n = idx % 256;
      Wu[idx] = pfnW1[(128 + k) * 256 + n] + pfnW1[(384 + k) * 256 + n];
      return;
    }
    idx -= 32768;
    if (idx < 32768) {  // Whjv f32 [128 k][256 n] = Whj - Wd
      int k = idx / 256, n = idx % 256;
      Whjv[idx] = pfnW1[(256 + k) * 256 + n] - pfnW1[(384 + k) * 256 + n];
      return;
    }
    idx -= 32768;
    if (idx < 32768) {  // W2T [128 n][256 k]
      int n = idx / 256, k = idx % 256;
      W2T[idx] = f2bf(pfnW2[k * 128 + n]);
      return;
    }
    idx -= 32768;
    if (idx < 65536) {  // W1Tp [512 n][128 k]
      int n = idx / 128, k = idx % 128;
      W1Tp[idx] = f2bf(pffW1[k * 512 + n]);
      return;
    }
    idx -= 65536;
    if (idx < 65536) {  // W2Tp [128 n][512 k]
      int n = idx / 512, k = idx % 512;
      W2Tp[idx] = f2bf(pffW2[k * 128 + n]);
    }
    return;
  }
  // ---- ctx (branch-free, unrolled) ----
  const int wg = blockIdx.x;
  const int half = t >> 7, d = t & 127;
  const bool outmode = wg < 1024;
  const int w2 = outmode ? wg : wg - 1024;
  const int b = w2 >> 8, x = w2 & 255;
  float acc = 0.f, deg = 0.f;
#pragma unroll 8
  for (int y0 = 0; y0 < 256; y0 += 2) {
    const int y = y0 + half;
    int row;
    if (outmode) row = (b * 256 + x) * 256 + y;
    else row = (b * 256 + y) * 256 + x;
    const float m = (float)edge_mask[row];
    const float v = pair_h[(long)row * 128 + d];
    acc = fmaf(m, v, acc);
    deg += m;
  }
  sacc[half][d] = acc;
  if (d == 0) sdeg[half] = deg;
  __syncthreads();
  if (t < 128) {
    float tot = sacc[0][d] + sacc[1][d];
    float dg = fmaxf(sdeg[0] + sdeg[1], 1.f);
    float* dst = outmode ? out_ctx : in_ctx;
    dst[(b * 256 + x) * 128 + d] = tot / dg;
  }
}

// ---------------------------------------------------------------------------
// K2: node path fp32 + fused u & hjv GEMVs (bf16 outputs) — R10 exact.
// ---------------------------------------------------------------------------
__global__ __launch_bounds__(256) void node_kernel(
    const float* __restrict__ node_h, const float* __restrict__ out_ctx,
    const float* __restrict__ in_ctx, const int* __restrict__ node_mask,
    const float* __restrict__ ogW, const float* __restrict__ ogb,
    const float* __restrict__ igW, const float* __restrict__ igb,
    const float* __restrict__ nW1, const float* __restrict__ nb1,
    const float* __restrict__ nW2, const float* __restrict__ nb2,
    const float* __restrict__ fW1, const float* __restrict__ fb1,
    const float* __restrict__ fW2, const float* __restrict__ fb2,
    const float* __restrict__ g1, const float* __restrict__ be1,
    const float* __restrict__ g2, const float* __restrict__ be2,
    const float* __restrict__ Wu, const float* __restrict__ ub1,
    const float* __restrict__ Whjv, float* __restrict__ out_node,
    short* __restrict__ node_bf, short* __restrict__ u_bf,
    short* __restrict__ hjv_bf) {
  __shared__ float sh[4][1792];
  __shared__ float fin[8][128];
  const int t = threadIdx.x;
  const int wv = t >> 6, lane = t & 63;
  float* const xn = sh[wv];
  float* const xo = sh[wv] + 256;
  float* const xi = sh[wv] + 512;
  float* const hh = sh[wv] + 768;
  const int row0 = blockIdx.x * 8 + wv * 2;

#pragma unroll
  for (int r = 0; r < 2; ++r) {
    const int row = row0 + r;
#pragma unroll
    for (int c = 0; c < 2; ++c) {
      const int col = lane + 64 * c;
      xn[r * 128 + col] = node_h[row * 128 + col];
      xo[r * 128 + col] = out_ctx[row * 128 + col];
      xi[r * 128 + col] = in_ctx[row * 128 + col];
    }
  }
  __syncthreads();

  {
    float ao[2][2], ai[2][2];
#pragma unroll
    for (int c = 0; c < 2; ++c) {
      const int col = lane + 64 * c;
      ao[0][c] = ao[1][c] = ogb[col];
      ai[0][c] = ai[1][c] = igb[col];
    }
    for (int k = 0; k < 256; ++k) {
      float xo0, xo1, xi0, xi1;
      if (k < 128) {
        xo0 = xi0 = xn[k];
        xo1 = xi1 = xn[128 + k];
      } else {
        xo0 = xo[k - 128]; xo1 = xo[k];
        xi0 = xi[k - 128]; xi1 = xi[k];
      }
#pragma unroll
      for (int c = 0; c < 2; ++c) {
        const int col = lane + 64 * c;
        const float wo = ogW[k * 128 + col], wi = igW[k * 128 + col];
        ao[0][c] += xo0 * wo; ao[1][c] += xo1 * wo;
        ai[0][c] += xi0 * wi; ai[1][c] += xi1 * wi;
      }
    }
#pragma unroll
    for (int c = 0; c < 2; ++c) {
      const int col = lane + 64 * c;
#pragma unroll
      for (int r = 0; r < 2; ++r) {
        const float go = 1.f / (1.f + __expf(-ao[r][c]));
        const float gi = 1.f / (1.f + __expf(-ai[r][c]));
        xo[r * 128 + col] *= go;
        xi[r * 128 + col] *= gi;
      }
    }
  }
  __syncthreads();

  {
    float a1[2][4];
#pragma unroll
    for (int c = 0; c < 4; ++c) {
      const int col = lane + 64 * c;
      a1[0][c] = a1[1][c] = nb1[col];
    }
    for (int k = 0; k < 384; ++k) {
      const float* src = (k < 128) ? xn : (k < 256) ? xo : xi;
      const int kk = k & 127;
      const float x0 = src[kk], x1 = src[128 + kk];
#pragma unroll
      for (int c = 0; c < 4; ++c) {
        const int col = lane + 64 * c;
        const float w = nW1[k * 256 + col];
        a1[0][c] += x0 * w; a1[1][c] += x1 * w;
      }
    }
#pragma unroll
    for (int c = 0; c < 4; ++c) {
      const int col = lane + 64 * c;
      hh[col] = gelu_f(a1[0][c]);
      hh[512 + col] = gelu_f(a1[1][c]);
    }
  }
  __syncthreads();
  {
    float a2[2][2];
#pragma unroll
    for (int c = 0; c < 2; ++c) {
      const int col = lane + 64 * c;
      a2[0][c] = a2[1][c] = nb2[col];
    }
    for (int k = 0; k < 256; ++k) {
      const float h0 = hh[k], h1 = hh[512 + k];
#pragma unroll
      for (int c = 0; c < 2; ++c) {
        const int col = lane + 64 * c;
        const float w = nW2[k * 128 + col];
        a2[0][c] += h0 * w; a2[1][c] += h1 * w;
      }
    }
#pragma unroll
    for (int r = 0; r < 2; ++r) {
      float v0 = xn[r * 128 + lane] + a2[r][0];
      float v1 = xn[r * 128 + lane + 64] + a2[r][1];
      float s = v0 + v1, ss = v0 * v0 + v1 * v1;
#pragma unroll
      for (int off = 1; off < 64; off <<= 1) {
        s += __shfl_xor(s, off, 64);
        ss += __shfl_xor(ss, off, 64);
      }
      const float m = s * (1.f / 128.f);
      const float var = ss * (1.f / 128.f) - m * m;
      const float rs = rsqrtf(var + 1e-5f);
      xn[r * 128 + lane] = (v0 - m) * rs * g1[lane] + be1[lane];
      xn[r * 128 + lane + 64] = (v1 - m) * rs * g1[lane + 64] + be1[lane + 64];
    }
  }
  __syncthreads();

  {
    float af[2][8];
#pragma unroll
    for (int c = 0; c < 8; ++c) {
      const int col = lane + 64 * c;
      af[0][c] = af[1][c] = fb1[col];
    }
    for (int k = 0; k < 128; ++k) {
      const float x0 = xn[k], x1 = xn[128 + k];
#pragma unroll
      for (int c = 0; c < 8; ++c) {
        const int col = lane + 64 * c;
        const float w = fW1[k * 512 + col];
        af[0][c] += x0 * w; af[1][c] += x1 * w;
      }
    }
#pragma unroll
    for (int c = 0; c < 8; ++c) {
      const int col = lane + 64 * c;
      hh[col] = gelu_f(af[0][c]);
      hh[512 + col] = gelu_f(af[1][c]);
    }
  }
  __syncthreads();
  {
    float a2[2][2];
#pragma unroll
    for (int c = 0; c < 2; ++c) {
      const int col = lane + 64 * c;
      a2[0][c] = a2[1][c] = fb2[col];
    }
    for (int k = 0; k < 512; ++k) {
      const float h0 = hh[k], h1 = hh[512 + k];
#pragma unroll
      for (int c = 0; c < 2; ++c) {
        const int col = lane + 64 * c;
        const float w = fW2[k * 128 + col];
        a2[0][c] += h0 * w; a2[1][c] += h1 * w;
      }
    }
#pragma unroll
    for (int r = 0; r < 2; ++r) {
      const int row = row0 + r;
      float v0 = xn[r * 128 + lane] + a2[r][0];
      float v1 = xn[r * 128 + lane + 64] + a2[r][1];
      float s = v0 + v1, ss = v0 * v0 + v1 * v1;
#pragma unroll
      for (int off = 1; off < 64; off <<= 1) {
        s += __shfl_xor(s, off, 64);
        ss += __shfl_xor(ss, off, 64);
      }
      const float m = s * (1.f / 128.f);
      const float var = ss * (1.f / 128.f) - m * m;
      const float rs = rsqrtf(var + 1e-5f);
      const float msk = (float)node_mask[row];
      const float o0 = ((v0 - m) * rs * g2[lane] + be2[lane]) * msk;
      const float o1 = ((v1 - m) * rs * g2[lane + 64] + be2[lane + 64]) * msk;
      out_node[row * 128 + lane] = o0;
      out_node[row * 128 + lane + 64] = o1;
      node_bf[row * 128 + lane] = f2bf(o0);
      node_bf[row * 128 + lane + 64] = f2bf(o1);
      fin[wv * 2 + r][lane] = o0;
      fin[wv * 2 + r][lane + 64] = o1;
    }
  }
  __syncthreads();
  // ---- u GEMV (includes b1) + hjv GEMV ----
  {
    float uacc[8], hacc[8];
    const float bb = ub1[t];
#pragma unroll
    for (int r = 0; r < 8; ++r) { uacc[r] = bb; hacc[r] = 0.f; }
#pragma unroll 4
    for (int k = 0; k < 128; ++k) {
      const float wu = Wu[k * 256 + t];
      const float wh = Whjv[k * 256 + t];
#pragma unroll
      for (int r = 0; r < 8; ++r) {
        uacc[r] += fin[r][k] * wu;
        hacc[r] += fin[r][k] * wh;
      }
    }
#pragma unroll
    for (int r = 0; r < 8; ++r) {
      u_bf[(blockIdx.x * 8 + r) * 256 + t] = f2bf(uacc[r]);
      hjv_bf[(blockIdx.x * 8 + r) * 256 + t] = f2bf(hacc[r]);
    }
  }
}

// ---------------------------------------------------------------------------
// K3: fused pair kernel (R10 exact — verified ~433us).
// 64-row tile, 512 thr, grid 4096, (512,4), 4-deep weight prefetch, 2-deep
// ds-read roll, padded pitches, 68KB LDS (2 blocks/CU).
// LDS: A/H1 [64][264] p528 @0; Y [64][136] p272 @0; H2 @33792; SCR @67584.
// ---------------------------------------------------------------------------
__global__ __launch_bounds__(512, 4) void pair_kernel(
    const float* __restrict__ pair_h, const short* __restrict__ node_bf,
    const int* __restrict__ edge_mask, const short* __restrict__ W1c,
    const short* __restrict__ W2T, const short* __restrict__ W1Tp,
    const short* __restrict__ W2Tp, const short* __restrict__ u_bf,
    const short* __restrict__ hjv_bf, const float* __restrict__ b2,
    const float* __restrict__ b1p, const float* __restrict__ b2p,
    const float* __restrict__ g1, const float* __restrict__ be1,
    const float* __restrict__ g2, const float* __restrict__ be2,
    float* __restrict__ out_pair) {
  constexpr int OFF_A = 0, OFF_H1 = 0, OFF_Y = 0, OFF_H2 = 33792,
                OFF_SCR = 67584;
  constexpr int PA = 528, PY = 272;  // byte pitches
  __shared__ __align__(16) char smem[69632];

  const int t = threadIdx.x;
  const int wg = blockIdx.x;
  const int b = wg >> 10, rem = wg & 1023;
  const int i = rem >> 2, j0 = (rem & 3) << 6;
  const int bi = (b << 8) + i;
  const long rowbase = (long)bi * 256 + j0;

  const int lane = t & 63, wv = t >> 6;
  const int lr = lane & 15, lq = lane >> 4;
  const int jb = (wv >> 2) * 32, nb2 = (wv & 3) * 32;

  // ---- P0: build A = [pair | hi*hj] bf16, padded pitch ----
  {
    const int r = t >> 3, oc = t & 7, c0 = oc * 16;
    const float* prow = pair_h + (rowbase + r) * 128 + c0;
    const short* hjrow = node_bf + (b * 256 + j0 + r) * 128 + c0;
    const short* hirow = node_bf + (b * 256 + i) * 128 + c0;
    char* arow = smem + OFF_A + r * PA;
#pragma unroll
    for (int h = 0; h < 2; ++h) {
      f32x4 p0 = *(const f32x4*)(prow + h * 8);
      f32x4 p1 = *(const f32x4*)(prow + h * 8 + 4);
      s16x8 hj = *(const s16x8*)(hjrow + h * 8);
      s16x8 hi = *(const s16x8*)(hirow + h * 8);
      *(s16x8*)(arow + c0 * 2 + h * 16) = pack8(p0, p1);
      union { u32x4 u; s16x8 s; } pd;
#pragma unroll
      for (int e = 0; e < 4; ++e)
        pd.u[e] = cvt_pk(bf2f(hi[2 * e]) * bf2f(hj[2 * e]),
                         bf2f(hi[2 * e + 1]) * bf2f(hj[2 * e + 1]));
      *(s16x8*)(arow + 256 + c0 * 2 + h * 16) = pd.s;
    }
  }
  __syncthreads();  // B1: A ready

  // ---- GEMM1: C1^T[n][j] over K=256; 4-deep w prefetch, 2-deep d roll ----
  f32x4 acc1[4][2];
#pragma unroll
  for (int jt = 0; jt < 4; ++jt)
#pragma unroll
    for (int nt = 0; nt < 2; ++nt) acc1[jt][nt] = {0.f, 0.f, 0.f, 0.f};
  {
    const int nb = wv * 32;
    const short* wp0 = W1c + (nb + lr) * 256 + lq * 8;
    const short* wp1 = W1c + (nb + 16 + lr) * 256 + lq * 8;
    s16x8 w0p[4], w1p[4];
#pragma unroll
    for (int pf = 0; pf < 4; ++pf) {
      w0p[pf] = *(const s16x8*)(wp0 + pf * 32);
      w1p[pf] = *(const s16x8*)(wp1 + pf * 32);
    }
    s16x8 dc[2][4];
#pragma unroll
    for (int pf = 0; pf < 2; ++pf)
#pragma unroll
      for (int jt = 0; jt < 4; ++jt)
        dc[pf][jt] = *(const s16x8*)(smem + OFF_A + (jt * 16 + lr) * PA +
                                     pf * 64 + lq * 16);
#pragma unroll
    for (int ks = 0; ks < 8; ++ks) {
      const int cur = ks & 1;
      s16x8 w0 = w0p[ks & 3], w1 = w1p[ks & 3];
      if (ks < 4) {
        w0p[ks & 3] = *(const s16x8*)(wp0 + (ks + 4) * 32);
        w1p[ks & 3] = *(const s16x8*)(wp1 + (ks + 4) * 32);
      }
      s16x8 d[4];
#pragma unroll
      for (int jt = 0; jt < 4; ++jt) d[jt] = dc[cur][jt];
      if (ks < 6) {
#pragma unroll
        for (int jt = 0; jt < 4; ++jt)
          dc[cur][jt] = *(const s16x8*)(smem + OFF_A + (jt * 16 + lr) * PA +
                                        (ks + 2) * 64 + lq * 16);
      }
#pragma unroll
      for (int jt = 0; jt < 4; ++jt) {
        acc1[jt][0] = __builtin_amdgcn_mfma_f32_16x16x32_bf16(w0, d[jt], acc1[jt][0], 0, 0, 0);
        acc1[jt][1] = __builtin_amdgcn_mfma_f32_16x16x32_bf16(w1, d[jt], acc1[jt][1], 0, 0, 0);
      }
    }
  }
  // pre-issue: u (H1 epilogue) + G2 first weights -- in flight across barrier
  s16x4 uv0 = *(const s16x4*)(u_bf + bi * 256 + wv * 32 + lq * 4);
  s16x4 uv1 = *(const s16x4*)(u_bf + bi * 256 + wv * 32 + 16 + lq * 4);
  const short* q2p0 = W2T + (nb2 + lr) * 256 + lq * 8;
  const short* q2p1 = W2T + (nb2 + 16 + lr) * 256 + lq * 8;
  s16x8 q2w0[4], q2w1[4];
  q2w0[0] = *(const s16x8*)q2p0;
  q2w1[0] = *(const s16x8*)q2p1;
  q2w0[1] = *(const s16x8*)(q2p0 + 32);
  q2w1[1] = *(const s16x8*)(q2p1 + 32);
  __syncthreads();  // B2: A reads done -> H1 overlay
  {
    const int nb = wv * 32;
#pragma unroll
    for (int nt = 0; nt < 2; ++nt) {
      const int n0 = nb + nt * 16 + lq * 4;
      const s16x4 uv = nt ? uv1 : uv0;
      f32x4 uu;
#pragma unroll
      for (int v = 0; v < 4; ++v) uu[v] = bf2f(uv[v]);  // u includes b1
#pragma unroll
      for (int jt = 0; jt < 4; ++jt) {
        const int j = jt * 16 + lr;
        s16x4 hv = *(const s16x4*)(hjv_bf + (b * 256 + j0 + j) * 256 + n0);
        float pre[4];
#pragma unroll
        for (int v = 0; v < 4; ++v)
          pre[v] = acc1[jt][nt][v] + uu[v] + bf2f(hv[v]);
        u32x2 pk = {cvt_pk(gelu_f(pre[0]), gelu_f(pre[1])),
                    cvt_pk(gelu_f(pre[2]), gelu_f(pre[3]))};
        *(u32x2*)(smem + OFF_H1 + j * PA + n0 * 2) = pk;
      }
    }
  }
  __syncthreads();  // B3: H1 ready

  // ---- GEMM2: x1^T[n][j] over K=256; wave -> (jb, nb2) 32x32 ----
  f32x4 x1v[2][2];
  {
    q2w0[2] = *(const s16x8*)(q2p0 + 64);
    q2w1[2] = *(const s16x8*)(q2p1 + 64);
    q2w0[3] = *(const s16x8*)(q2p0 + 96);
    q2w1[3] = *(const s16x8*)(q2p1 + 96);
    f32x4 pr[2][2];
#pragma unroll
    for (int nt = 0; nt < 2; ++nt)
#pragma unroll
      for (int jt = 0; jt < 2; ++jt)
        pr[jt][nt] = *(const f32x4*)(pair_h + (rowbase + jb + jt * 16 + lr) * 128 +
                                     nb2 + nt * 16 + lq * 4);
    s16x8 dc[2][2];
#pragma unroll
    for (int pf = 0; pf < 2; ++pf)
#pragma unroll
      for (int jt = 0; jt < 2; ++jt)
        dc[pf][jt] = *(const s16x8*)(smem + OFF_H1 + (jb + jt * 16 + lr) * PA +
                                     pf * 64 + lq * 16);
    f32x4 acc2[2][2];
#pragma unroll
    for (int jt = 0; jt < 2; ++jt)
#pragma unroll
      for (int nt = 0; nt < 2; ++nt) acc2[jt][nt] = {0.f, 0.f, 0.f, 0.f};
#pragma unroll
    for (int ks = 0; ks < 8; ++ks) {
      const int cur = ks & 1;
      s16x8 w0 = q2w0[ks & 3], w1 = q2w1[ks & 3];
      if (ks < 4) {
        q2w0[ks & 3] = *(const s16x8*)(q2p0 + (ks + 4) * 32);
        q2w1[ks & 3] = *(const s16x8*)(q2p1 + (ks + 4) * 32);
      }
      s16x8 d[2];
#pragma unroll
      for (int jt = 0; jt < 2; ++jt) d[jt] = dc[cur][jt];
      if (ks < 6) {
#pragma unroll
        for (int jt = 0; jt < 2; ++jt)
          dc[cur][jt] = *(const s16x8*)(smem + OFF_H1 + (jb + jt * 16 + lr) * PA +
                                        (ks + 2) * 64 + lq * 16);
      }
#pragma unroll
      for (int jt = 0; jt < 2; ++jt) {
        acc2[jt][0] = __builtin_amdgcn_mfma_f32_16x16x32_bf16(w0, d[jt], acc2[jt][0], 0, 0, 0);
        acc2[jt][1] = __builtin_amdgcn_mfma_f32_16x16x32_bf16(w1, d[jt], acc2[jt][1], 0, 0, 0);
      }
    }
#pragma unroll
    for (int nt = 0; nt < 2; ++nt) {
      const int n0 = nb2 + nt * 16 + lq * 4;
      f32x4 bv = *(const f32x4*)(b2 + n0);
#pragma unroll
      for (int jt = 0; jt < 2; ++jt)
        x1v[jt][nt] = acc2[jt][nt] + bv + pr[jt][nt];
    }
  }
  // ---- LN1 in-reg ----
  {
    float s[2], ss[2];
#pragma unroll
    for (int jt = 0; jt < 2; ++jt) {
      s[jt] = 0.f; ss[jt] = 0.f;
#pragma unroll
      for (int nt = 0; nt < 2; ++nt)
#pragma unroll
        for (int v = 0; v < 4; ++v) {
          const float x = x1v[jt][nt][v];
          s[jt] += x; ss[jt] += x * x;
        }
      s[jt] += __shfl_xor(s[jt], 16, 64);
      ss[jt] += __shfl_xor(ss[jt], 16, 64);
      s[jt] += __shfl_xor(s[jt], 32, 64);
      ss[jt] += __shfl_xor(ss[jt], 32, 64);
    }
    if (lq == 0) {
#pragma unroll
      for (int jt = 0; jt < 2; ++jt) {
        const int j = jb + jt * 16 + lr;
        f32x2 p = {s[jt], ss[jt]};
        *(f32x2*)(smem + OFF_SCR + j * 32 + (wv & 3) * 8) = p;
      }
    }
    __syncthreads();  // B4: H1 reads done + SCR partials visible
    float lnm[2], lnr[2];
#pragma unroll
    for (int jt = 0; jt < 2; ++jt) {
      const int j = jb + jt * 16 + lr;
      f32x4 pA = *(const f32x4*)(smem + OFF_SCR + j * 32);
      f32x4 pB = *(const f32x4*)(smem + OFF_SCR + j * 32 + 16);
      const float S = pA[0] + pA[2] + pB[0] + pB[2];
      const float SS = pA[1] + pA[3] + pB[1] + pB[3];
      const float m = S * (1.f / 128.f);
      const float var = SS * (1.f / 128.f) - m * m;
      lnm[jt] = m;
      lnr[jt] = rsqrtf(var + 1e-5f);
    }
#pragma unroll
    for (int nt = 0; nt < 2; ++nt) {
      const int n0 = nb2 + nt * 16 + lq * 4;
      f32x4 gv = *(const f32x4*)(g1 + n0);
      f32x4 bv = *(const f32x4*)(be1 + n0);
#pragma unroll
      for (int jt = 0; jt < 2; ++jt) {
        const int j = jb + jt * 16 + lr;
        float y[4];
#pragma unroll
        for (int v = 0; v < 4; ++v)
          y[v] = (x1v[jt][nt][v] - lnm[jt]) * lnr[jt] * gv[v] + bv[v];
        u32x2 pk = {cvt_pk(y[0], y[1]), cvt_pk(y[2], y[3])};
        *(u32x2*)(smem + OFF_Y + j * PY + n0 * 2) = pk;
      }
    }
  }
  // pre-issue G3-p0 first weights + edge_mask before the barrier
  const short* g3p0a = W1Tp + (wv * 32 + lr) * 128 + lq * 8;
  const short* g3p1a = W1Tp + (wv * 32 + 16 + lr) * 128 + lq * 8;
  s16x8 g3w0[4], g3w1[4];
  g3w0[0] = *(const s16x8*)g3p0a;
  g3w1[0] = *(const s16x8*)g3p1a;
  g3w0[1] = *(const s16x8*)(g3p0a + 32);
  g3w1[1] = *(const s16x8*)(g3p1a + 32);
  const int em0 = edge_mask[rowbase + jb + lr];
  const int em1 = edge_mask[rowbase + jb + 16 + lr];
  __syncthreads();  // B5: Y ready

  // ---- pff: 2 K-halves; per half GEMM3(K=128)->H2half, GEMM4 accumulates ----
  f32x4 acc4[2][2];
#pragma unroll
  for (int jt = 0; jt < 2; ++jt)
#pragma unroll
    for (int nt = 0; nt < 2; ++nt) acc4[jt][nt] = {0.f, 0.f, 0.f, 0.f};

#pragma unroll
  for (int p = 0; p < 2; ++p) {
    f32x4 acc3[4][2];
#pragma unroll
    for (int jt = 0; jt < 4; ++jt)
#pragma unroll
      for (int nt = 0; nt < 2; ++nt) acc3[jt][nt] = {0.f, 0.f, 0.f, 0.f};
    {
      const int nb3 = p * 256 + wv * 32;
      const short* wp0 = W1Tp + (nb3 + lr) * 128 + lq * 8;
      const short* wp1 = W1Tp + (nb3 + 16 + lr) * 128 + lq * 8;
      if (p == 0) {  // slots 0,1 pre-issued before barrier B5
        g3w0[2] = *(const s16x8*)(wp0 + 64);
        g3w1[2] = *(const s16x8*)(wp1 + 64);
        g3w0[3] = *(const s16x8*)(wp0 + 96);
        g3w1[3] = *(const s16x8*)(wp1 + 96);
      } else {
#pragma unroll
        for (int pf = 0; pf < 4; ++pf) {
          g3w0[pf] = *(const s16x8*)(wp0 + pf * 32);
          g3w1[pf] = *(const s16x8*)(wp1 + pf * 32);
        }
      }
#pragma unroll
      for (int ks = 0; ks < 4; ++ks) {
        s16x8 d[4];
#pragma unroll
        for (int jt = 0; jt < 4; ++jt)
          d[jt] = *(const s16x8*)(smem + OFF_Y + (jt * 16 + lr) * PY +
                                  ks * 64 + lq * 16);
#pragma unroll
        for (int jt = 0; jt < 4; ++jt) {
          acc3[jt][0] = __builtin_amdgcn_mfma_f32_16x16x32_bf16(g3w0[ks], d[jt], acc3[jt][0], 0, 0, 0);
          acc3[jt][1] = __builtin_amdgcn_mfma_f32_16x16x32_bf16(g3w1[ks], d[jt], acc3[jt][1], 0, 0, 0);
        }
      }
    }
    // pre-issue G4 weights for this half (in flight across H2-write + barrier)
    const short* qp0 = W2Tp + (nb2 + lr) * 512 + p * 256 + lq * 8;
    const short* qp1 = W2Tp + (nb2 + 16 + lr) * 512 + p * 256 + lq * 8;
    s16x8 q4w0[4], q4w1[4];
    q4w0[0] = *(const s16x8*)qp0;
    q4w1[0] = *(const s16x8*)qp1;
    q4w0[1] = *(const s16x8*)(qp0 + 32);
    q4w1[1] = *(const s16x8*)(qp1 + 32);
    if (p == 1) __syncthreads();  // B7: G4-p0 H2 reads done before overwrite
    {
#pragma unroll
      for (int nt = 0; nt < 2; ++nt) {
        const int n0l = wv * 32 + nt * 16 + lq * 4;  // local n within half
        f32x4 bv = *(const f32x4*)(b1p + p * 256 + n0l);
#pragma unroll
        for (int jt = 0; jt < 4; ++jt) {
          const int j = jt * 16 + lr;
          u32x2 pk = {cvt_pk(gelu_f(acc3[jt][nt][0] + bv[0]),
                             gelu_f(acc3[jt][nt][1] + bv[1])),
                      cvt_pk(gelu_f(acc3[jt][nt][2] + bv[2]),
                             gelu_f(acc3[jt][nt][3] + bv[3]))};
          *(u32x2*)(smem + OFF_H2 + j * PA + n0l * 2) = pk;
        }
      }
    }
    __syncthreads();  // B6/B8: H2 half ready
    {
      q4w0[2] = *(const s16x8*)(qp0 + 64);
      q4w1[2] = *(const s16x8*)(qp1 + 64);
      q4w0[3] = *(const s16x8*)(qp0 + 96);
      q4w1[3] = *(const s16x8*)(qp1 + 96);
      s16x8 dc[2][2];
#pragma unroll
      for (int pf = 0; pf < 2; ++pf)
#pragma unroll
        for (int jt = 0; jt < 2; ++jt)
          dc[pf][jt] = *(const s16x8*)(smem + OFF_H2 + (jb + jt * 16 + lr) * PA +
                                       pf * 64 + lq * 16);
#pragma unroll
      for (int ks = 0; ks < 8; ++ks) {
        const int cur = ks & 1;
        s16x8 w0 = q4w0[ks & 3], w1 = q4w1[ks & 3];
        if (ks < 4) {
          q4w0[ks & 3] = *(const s16x8*)(qp0 + (ks + 4) * 32);
          q4w1[ks & 3] = *(const s16x8*)(qp1 + (ks + 4) * 32);
        }
        s16x8 d[2];
#pragma unroll
        for (int jt = 0; jt < 2; ++jt) d[jt] = dc[cur][jt];
        if (ks < 6) {
#pragma unroll
          for (int jt = 0; jt < 2; ++jt)
            dc[cur][jt] = *(const s16x8*)(smem + OFF_H2 + (jb + jt * 16 + lr) * PA +
                                          (ks + 2) * 64 + lq * 16);
        }
#pragma unroll
        for (int jt = 0; jt < 2; ++jt) {
          acc4[jt][0] = __builtin_amdgcn_mfma_f32_16x16x32_bf16(w0, d[jt], acc4[jt][0], 0, 0, 0);
          acc4[jt][1] = __builtin_amdgcn_mfma_f32_16x16x32_bf16(w1, d[jt], acc4[jt][1], 0, 0, 0);
        }
      }
    }
  }

  // ---- x2 = y + G4 + b2p; LN2 + edge mask + store ----
  f32x4 x2v[2][2];
#pragma unroll
  for (int nt = 0; nt < 2; ++nt) {
    const int n0 = nb2 + nt * 16 + lq * 4;
    f32x4 bv = *(const f32x4*)(b2p + n0);
#pragma unroll
    for (int jt = 0; jt < 2; ++jt) {
      const int j = jb + jt * 16 + lr;
      s16x4 yv = *(const s16x4*)(smem + OFF_Y + j * PY + n0 * 2);
      f32x4 yr;
#pragma unroll
      for (int v = 0; v < 4; ++v) yr[v] = bf2f(yv[v]);
      x2v[jt][nt] = acc4[jt][nt] + bv + yr;
    }
  }
  {
    float s[2], ss[2];
#pragma unroll
    for (int jt = 0; jt < 2; ++jt) {
      s[jt] = 0.f; ss[jt] = 0.f;
#pragma unroll
      for (int nt = 0; nt < 2; ++nt)
#pragma unroll
        for (int v = 0; v < 4; ++v) {
          const float x = x2v[jt][nt][v];
          s[jt] += x; ss[jt] += x * x;
        }
      s[jt] += __shfl_xor(s[jt], 16, 64);
      ss[jt] += __shfl_xor(ss[jt], 16, 64);
      s[jt] += __shfl_xor(s[jt], 32, 64);
      ss[jt] += __shfl_xor(ss[jt], 32, 64);
    }
    // SCR last read before B5 by all waves -> safe to overwrite
    if (lq == 0) {
#pragma unroll
      for (int jt = 0; jt < 2; ++jt) {
        const int j = jb + jt * 16 + lr;
        f32x2 p = {s[jt], ss[jt]};
        *(f32x2*)(smem + OFF_SCR + j * 32 + (wv & 3) * 8) = p;
      }
    }
    __syncthreads();  // B9
    float lnm[2], lnr[2], vp[2];
#pragma unroll
    for (int jt = 0; jt < 2; ++jt) {
      const int j = jb + jt * 16 + lr;
      f32x4 pA = *(const f32x4*)(smem + OFF_SCR + j * 32);
      f32x4 pB = *(const f32x4*)(smem + OFF_SCR + j * 32 + 16);
      const float S = pA[0] + pA[2] + pB[0] + pB[2];
      const float SS = pA[1] + pA[3] + pB[1] + pB[3];
      const float m = S * (1.f / 128.f);
      const float var = SS * (1.f / 128.f) - m * m;
      lnm[jt] = m;
      lnr[jt] = rsqrtf(var + 1e-5f);
      vp[jt] = (float)(jt ? em1 : em0);
    }
#pragma unroll
    for (int nt = 0; nt < 2; ++nt) {
      const int n0 = nb2 + nt * 16 + lq * 4;
      f32x4 gv = *(const f32x4*)(g2 + n0);
      f32x4 bv = *(const f32x4*)(be2 + n0);
#pragma unroll
      for (int jt = 0; jt < 2; ++jt) {
        const int j = jb + jt * 16 + lr;
        f32x4 o;
#pragma unroll
        for (int v = 0; v < 4; ++v)
          o[v] = ((x2v[jt][nt][v] - lnm[jt]) * lnr[jt] * gv[v] + bv[v]) * vp[jt];
        *(f32x4*)(out_pair + (rowbase + j) * 128 + n0) = o;
      }
    }
  }
}

// ---------------------------------------------------------------------------
extern "C" void kernel_launch(void* const* d_in, const int* in_sizes, int n_in,
                              void* d_out, int out_size, void* d_ws,
                              size_t ws_size, hipStream_t stream) {
  const float* node_h = (const float*)d_in[0];
  const float* pair_h = (const float*)d_in[1];
  const int* node_mask = (const int*)d_in[2];
  const int* edge_mask = (const int*)d_in[3];
  const float* nfp_W1 = (const float*)d_in[4];
  const float* nfp_b1 = (const float*)d_in[5];
  const float* nfp_W2 = (const float*)d_in[6];
  const float* nfp_b2 = (const float*)d_in[7];
  const float* pfn_W1 = (const float*)d_in[8];
  const float* pfn_b1 = (const float*)d_in[9];
  const float* pfn_W2 = (const float*)d_in[10];
  const float* pfn_b2 = (const float*)d_in[11];
  const float* nff_W1 = (const float*)d_in[12];
  const float* nff_b1 = (const float*)d_in[13];
  const float* nff_W2 = (const float*)d_in[14];
  const float* nff_b2 = (const float*)d_in[15];
  const float* pff_W1 = (const float*)d_in[16];
  const float* pff_b1 = (const float*)d_in[17];
  const float* pff_W2 = (const float*)d_in[18];
  const float* pff_b2 = (const float*)d_in[19];
  const float* og_W = (const float*)d_in[20];
  const float* og_b = (const float*)d_in[21];
  const float* ig_W = (const float*)d_in[22];
  const float* ig_b = (const float*)d_in[23];
  const float* nn1_g = (const float*)d_in[24];
  const float* nn1_b = (const float*)d_in[25];
  const float* nn2_g = (const float*)d_in[26];
  const float* nn2_b = (const float*)d_in[27];
  const float* pn1_g = (const float*)d_in[28];
  const float* pn1_b = (const float*)d_in[29];
  const float* pn2_g = (const float*)d_in[30];
  const float* pn2_b = (const float*)d_in[31];

  char* ws = (char*)d_ws;
  short* W1c = (short*)(ws);                 // 131072
  short* W2T = (short*)(ws + 131072);        // 65536
  short* W1Tp = (short*)(ws + 196608);       // 131072
  short* W2Tp = (short*)(ws + 327680);       // 131072
  float* Wu = (float*)(ws + 458752);         // 131072
  float* Whjv = (float*)(ws + 589824);       // 131072
  float* out_ctx = (float*)(ws + 720896);    // 524288
  float* in_ctx = (float*)(ws + 1245184);    // 524288
  short* node_bf = (short*)(ws + 1769472);   // 262144
  short* u_bf = (short*)(ws + 2031616);      // 524288
  short* hjv_bf = (short*)(ws + 2555904);    // 524288 -> ends 3080192

  float* out_node = (float*)d_out;
  float* out_pair = (float*)d_out + 131072;

  prep_ctx_kernel<<<3200, 256, 0, stream>>>(
      pair_h, edge_mask, pfn_W1, pfn_W2, pff_W1, pff_W2, W1c, Wu, Whjv, W2T,
      W1Tp, W2Tp, out_ctx, in_ctx);
  node_kernel<<<128, 256, 0, stream>>>(
      node_h, out_ctx, in_ctx, node_mask, og_W, og_b, ig_W, ig_b, nfp_W1,
      nfp_b1, nfp_W2, nfp_b2, nff_W1, nff_b1, nff_W2, nff_b2, nn1_g, nn1_b,
      nn2_g, nn2_b, Wu, pfn_b1, Whjv, out_node, node_bf, u_bf, hjv_bf);
  pair_kernel<<<4096, 512, 0, stream>>>(
      pair_h, node_bf, edge_mask, W1c, W2T, W1Tp, W2Tp, u_bf, hjv_bf, pfn_b2,
      pff_b1, pff_b2, pn1_g, pn1_b, pn2_g, pn2_b, out_pair);
}